// Round 9
// baseline (226.670 us; speedup 1.0000x reference)
//
#include <hip/hip_runtime.h>
#include <cstddef>

#define Bb    4
#define Sq    2048
#define Dd    256
#define Hh    4
#define HDh   64
#define NROWS (Bb*Sq)     // 8192
#define EPSf  1e-5f

typedef unsigned short u16;
typedef unsigned int   u32;
typedef unsigned long long u64;
typedef __attribute__((ext_vector_type(8))) short  frag_ab;  // 8 bf16 (4 VGPRs)
typedef __attribute__((ext_vector_type(4))) float  frag_cd;  // 4 fp32

__device__ __forceinline__ u16 f2bf(float f){
    union { float f; u32 u; } v; v.f = f;
    u32 r = v.u + 0x7fffu + ((v.u >> 16) & 1u);   // RNE
    return (u16)(r >> 16);
}
__device__ __forceinline__ u16 f2bf_trunc(float f){
    union { float f; u32 u; } v; v.f = f;
    return (u16)(v.u >> 16);                      // 1-op truncation
}
__device__ __forceinline__ float bf2f(u32 u){
    union { u32 u; float f; } v; v.u = u << 16; return v.f;
}

// ---------------------------------------------------------------------------
// K0: prep. blocks 0..79: transpose+convert 5 weights -> wT[n][k] bf16.
//     blocks 80..335: RoPE table tab[s][0..31]=cos, [32..63]=sin.
// ---------------------------------------------------------------------------
__global__ __launch_bounds__(256) void k0_prep(
    const float* __restrict__ w_in, const float* __restrict__ wq,
    const float* __restrict__ wk,   const float* __restrict__ wv,
    const float* __restrict__ wo,
    u16* __restrict__ wT, float* __restrict__ tab)
{
    const int bid = blockIdx.x, tid = threadIdx.x;
    if (bid < 80){
        __shared__ float T[64][65];
        const int wsel = bid >> 4, tile = bid & 15;
        const int k0 = (tile >> 2) * 64, n0 = (tile & 3) * 64;
        const float* src = wsel==0 ? w_in : wsel==1 ? wq : wsel==2 ? wk
                         : wsel==3 ? wv : wo;
        #pragma unroll
        for (int i=0;i<16;++i){
            int idx = i*256 + tid, k = idx>>6, n = idx&63;
            T[k][n] = src[(size_t)(k0+k)*Dd + n0 + n];
        }
        __syncthreads();
        u16* dst = wT + (size_t)wsel*Dd*Dd;
        #pragma unroll
        for (int i=0;i<16;++i){
            int idx = i*256 + tid, n = idx>>6, k = idx&63;
            dst[(size_t)(n0+n)*Dd + k0 + k] = f2bf(T[k][n]);
        }
    } else {
        int s = (bid-80)*8 + (tid>>5);
        int p = tid & 31;
        float invf = exp2f(-(float)p * (13.287712379549449f/32.f)); // log2(1e4)/32
        float sn, cs; sincosf((float)s * invf, &sn, &cs);
        tab[(size_t)s*64 + p]      = cs;
        tab[(size_t)s*64 + 32 + p] = sn;
    }
}

// ---------------------------------------------------------------------------
// K1 fused: stage x -> in-proj -> LN1 -> q/k/v -> RoPE / V^T.
// 8 rows/block, 1024 blocks (4 blocks/CU, 16 waves/CU for latency hiding).
// MFMA M=16 half-idle (tokens 8-15 zero) — MFMA is <5% of kernel time.
// Swapped operands: lane holds token=l16 x 16 contiguous cols.
// ---------------------------------------------------------------------------
__global__ __launch_bounds__(256) void k1_fused(
    const float* __restrict__ x,  const float* __restrict__ tab,
    const u16* __restrict__ wTin, const u16* __restrict__ wTq,
    const u16* __restrict__ wTk,  const u16* __restrict__ wTv,
    const float* __restrict__ b_in, const float* __restrict__ g1,
    const float* __restrict__ be1,  const float* __restrict__ bq,
    const float* __restrict__ bk,   const float* __restrict__ bv,
    float* __restrict__ x1, u16* __restrict__ qro,
    u16* __restrict__ kro,  u16* __restrict__ vto)
{
    const int tid  = threadIdx.x;
    const int w    = tid >> 6;
    const int lane = tid & 63;
    const int l16  = lane & 15;
    const int quad = lane >> 4;
    const int r0   = blockIdx.x * 8;
    const int b    = r0 >> 11;
    const int s0   = r0 & (Sq-1);
    const int cb   = w * 64;              // wave's column base
    const int c4   = cb + quad*4;         // lane's first column (per nt: +nt*16)

    __shared__ u16 Xs[16][264];
    __shared__ u16 Hs[16][264];
    __shared__ u16 Os[16][264];
    __shared__ float red[2][16][4];

    // stage x tile rows 0-7 (fp32->bf16); rows 8-15 zeroed
    #pragma unroll
    for (int i=0;i<4;++i){
        int f = i*256 + tid;
        int row = f>>6, cc = f&63;
        u64 val = 0;
        if (row < 8){
            float4 v4 = *(const float4*)(x + (size_t)(r0+row)*Dd + cc*4);
            u16 pk4[4] = { f2bf(v4.x), f2bf(v4.y), f2bf(v4.z), f2bf(v4.w) };
            val = *(u64*)pk4;
        }
        *(u64*)&Xs[row][cc*4] = val;
    }
    __syncthreads();

    // in-proj: acc[nt] holds y[token=l16][n=c4+nt*16 .. +3]
    frag_cd acc[4];
    #pragma unroll
    for (int nt=0;nt<4;++nt){
        float4 b4 = *(const float4*)&b_in[c4 + nt*16];
        acc[nt] = (frag_cd){b4.x, b4.y, b4.z, b4.w};
    }
    #pragma unroll
    for (int kc=0;kc<8;++kc){
        frag_ab xa = *(frag_ab*)&Xs[l16][kc*32 + quad*8];
        #pragma unroll
        for (int nt=0;nt<4;++nt){
            frag_ab wf = *(const frag_ab*)&wTin[(size_t)(cb+nt*16+l16)*Dd + kc*32 + quad*8];
            acc[nt] = __builtin_amdgcn_mfma_f32_16x16x32_bf16(wf, xa, acc[nt], 0,0,0);
        }
    }

    // x1 store (float4, rows 0-7 only) + LN1 partial sums
    float s=0.f, q=0.f;
    #pragma unroll
    for (int nt=0;nt<4;++nt){
        float4 v4 = make_float4(acc[nt][0], acc[nt][1], acc[nt][2], acc[nt][3]);
        if (l16 < 8)
            *(float4*)&x1[(size_t)(r0+l16)*Dd + c4 + nt*16] = v4;
        s += v4.x+v4.y+v4.z+v4.w;
        q += v4.x*v4.x + v4.y*v4.y + v4.z*v4.z + v4.w*v4.w;
    }
    s += __shfl_xor(s,16); q += __shfl_xor(q,16);
    s += __shfl_xor(s,32); q += __shfl_xor(q,32);
    if (lane < 8){ red[0][l16][w]=s; red[1][l16][w]=q; }
    __syncthreads();

    {   // rows 8-15 read garbage red -> NaN Hs rows, never consumed downstream
        float mu = (red[0][l16][0]+red[0][l16][1]+red[0][l16][2]+red[0][l16][3])*(1.f/Dd);
        float ms = (red[1][l16][0]+red[1][l16][1]+red[1][l16][2]+red[1][l16][3])*(1.f/Dd);
        float rstd = rsqrtf(ms - mu*mu + EPSf);
        #pragma unroll
        for (int nt=0;nt<4;++nt){
            float4 g4 = *(const float4*)&g1[c4 + nt*16];
            float4 e4 = *(const float4*)&be1[c4 + nt*16];
            u16 pk4[4] = { f2bf((acc[nt][0]-mu)*rstd*g4.x + e4.x),
                           f2bf((acc[nt][1]-mu)*rstd*g4.y + e4.y),
                           f2bf((acc[nt][2]-mu)*rstd*g4.z + e4.z),
                           f2bf((acc[nt][3]-mu)*rstd*g4.w + e4.w) };
            *(u64*)&Hs[l16][c4 + nt*16] = *(u64*)pk4;
        }
    }
    __syncthreads();

    const u16*   wps[3] = { wTq, wTk, wTv };
    const float* bps[3] = { bq, bk, bv };
    #pragma unroll
    for (int tt=0; tt<3; ++tt){
        frag_cd a2[4];
        #pragma unroll
        for (int nt=0;nt<4;++nt){
            float4 b4 = *(const float4*)&bps[tt][c4 + nt*16];
            a2[nt] = (frag_cd){b4.x, b4.y, b4.z, b4.w};
        }
        #pragma unroll
        for (int kc=0;kc<8;++kc){
            frag_ab ha = *(frag_ab*)&Hs[l16][kc*32 + quad*8];
            #pragma unroll
            for (int nt=0;nt<4;++nt){
                frag_ab wf = *(const frag_ab*)&wps[tt][(size_t)(cb+nt*16+l16)*Dd + kc*32 + quad*8];
                a2[nt] = __builtin_amdgcn_mfma_f32_16x16x32_bf16(wf, ha, a2[nt], 0,0,0);
            }
        }
        #pragma unroll
        for (int nt=0;nt<4;++nt){
            u16 pk4[4] = { f2bf(a2[nt][0]), f2bf(a2[nt][1]),
                           f2bf(a2[nt][2]), f2bf(a2[nt][3]) };
            *(u64*)&Os[l16][c4 + nt*16] = *(u64*)pk4;
        }
        __syncthreads();

        if (tt < 2){
            // RoPE via table: thread -> (row 0-7, head, p-chunk of 4)
            const int row  = tid >> 5;
            const int head = (tid >> 3) & 3;
            const int pq   = tid & 7;
            const int sidx = s0 + row;
            const float* tb = tab + (size_t)sidx*64;
            float4 c4v = *(const float4*)(tb + pq*4);
            float4 s4v = *(const float4*)(tb + 32 + pq*4);
            const float cA[4] = {c4v.x,c4v.y,c4v.z,c4v.w};
            const float sA[4] = {s4v.x,s4v.y,s4v.z,s4v.w};
            u16* dst = (tt==0 ? qro : kro) + ((size_t)(b*Hh+head)*Sq + sidx)*HDh;
            u16 lo[4], hi[4];
            #pragma unroll
            for (int j=0;j<4;++j){
                int p = pq*4 + j;
                u32 pr = *(const u32*)&Os[row][head*64 + 2*p];
                float t0 = bf2f(pr & 0xffffu), t1 = bf2f(pr >> 16);
                lo[j] = f2bf(t0*cA[j] - t1*sA[j]);
                hi[j] = f2bf(t1*cA[j] + t0*sA[j]);
            }
            *(u64*)(dst + pq*4)      = *(u64*)lo;
            *(u64*)(dst + 32 + pq*4) = *(u64*)hi;
        } else {
            // V transpose: thread -> (head, d); 8 tokens -> one 16B store
            const int head = tid >> 6, d = lane;
            u16 pk[8];
            #pragma unroll
            for (int j=0;j<8;++j) pk[j] = Os[j][head*64 + d];
            u16* dst = vto + ((size_t)(b*Hh+head)*HDh + d)*Sq + s0;
            *(float4*)dst = *(float4*)pk;
        }
        __syncthreads();
    }
}

// ---------------------------------------------------------------------------
// K2: bf16 MFMA flash attention. 128-query blocks (8 waves, 512 thr),
// split-K x4 -> 1024 blocks = 4/CU = 32 waves/CU. Q fragments direct from
// global; K/V staged in LDS. Fixed-max softmax; bf16 O partials.
// ---------------------------------------------------------------------------
__global__ __launch_bounds__(512) void k2_attn(
    const u16* __restrict__ qr, const u16* __restrict__ kr,
    const u16* __restrict__ vt, const int* __restrict__ mask,
    u16* __restrict__ Opart, float* __restrict__ lpart)
{
    const int tid = threadIdx.x;
    const int w   = tid >> 6;          // 0..7
    const int lane= tid & 63;
    const int l16 = lane & 15;
    const int quad= lane >> 4;
    const int qt  = blockIdx.x;        // 0..15
    const int bh  = blockIdx.y;        // 0..15
    const int ks  = blockIdx.z;        // 0..3 split over keys (512 each)
    const int b   = bh >> 2;
    const int q0  = qt * 128;

    __shared__ u16 Ks [64][72];
    __shared__ u16 Vts[64][72];
    __shared__ u16 Ps [8][16][72];

    const u16* qg = qr + ((size_t)bh*Sq + q0 + w*16 + l16)*HDh;
    frag_ab qf0 = *(const frag_ab*)(qg + quad*8);
    frag_ab qf1 = *(const frag_ab*)(qg + quad*8 + 32);

    const float mf2 = (mask[(size_t)b*Sq + q0 + w*16 + l16] != 0)
                    ? 0.125f*1.44269504f : 0.f;

    float lsum = 0.f;
    frag_cd O[4];
    #pragma unroll
    for (int d=0; d<4; ++d) O[d] = (frag_cd){0.f,0.f,0.f,0.f};

    const u16* kg0 = kr + ((size_t)bh*Sq + ks*512)*HDh;
    const u16* vg0 = vt + (size_t)bh*HDh*Sq + ks*512;

    const int srow = tid >> 3, spart = tid & 7;

    for (int kt=0; kt<8; ++kt){
        __syncthreads();
        const u16* kg = kg0 + (size_t)kt*64*HDh;
        const u16* vg = vg0 + kt*64;
        *(float4*)&Ks [srow][spart*8] = *(const float4*)(kg + srow*HDh + spart*8);
        *(float4*)&Vts[srow][spart*8] = *(const float4*)(vg + (size_t)srow*Sq + spart*8);
        __syncthreads();

        frag_cd sc[4];
        #pragma unroll
        for (int t=0;t<4;++t){
            frag_ab kf0 = *(frag_ab*)&Ks[t*16 + l16][quad*8];
            frag_ab kf1 = *(frag_ab*)&Ks[t*16 + l16][quad*8 + 32];
            frag_cd z = (frag_cd){0.f,0.f,0.f,0.f};
            z = __builtin_amdgcn_mfma_f32_16x16x32_bf16(kf0, qf0, z, 0,0,0);
            z = __builtin_amdgcn_mfma_f32_16x16x32_bf16(kf1, qf1, z, 0,0,0);
            sc[t] = z;
        }

        #pragma unroll
        for (int t=0;t<4;++t){
            float p0 = exp2f(sc[t][0]*mf2);
            float p1 = exp2f(sc[t][1]*mf2);
            float p2 = exp2f(sc[t][2]*mf2);
            float p3 = exp2f(sc[t][3]*mf2);
            lsum += p0+p1+p2+p3;
            u16 pk4[4] = { f2bf_trunc(p0), f2bf_trunc(p1),
                           f2bf_trunc(p2), f2bf_trunc(p3) };
            *(u64*)&Ps[w][l16][t*16 + quad*4] = *(u64*)pk4;
        }

        frag_ab pf0 = *(frag_ab*)&Ps[w][l16][quad*8];
        frag_ab pf1 = *(frag_ab*)&Ps[w][l16][quad*8 + 32];

        #pragma unroll
        for (int d=0; d<4; ++d){
            frag_ab vf0 = *(frag_ab*)&Vts[d*16 + l16][quad*8];
            frag_ab vf1 = *(frag_ab*)&Vts[d*16 + l16][quad*8 + 32];
            O[d] = __builtin_amdgcn_mfma_f32_16x16x32_bf16(vf0, pf0, O[d], 0,0,0);
            O[d] = __builtin_amdgcn_mfma_f32_16x16x32_bf16(vf1, pf1, O[d], 0,0,0);
        }
    }

    u16* Ob = Opart + (((size_t)ks*16 + bh)*Sq + q0 + w*16 + l16)*HDh;
    #pragma unroll
    for (int dt=0; dt<4; ++dt){
        u16 pk4[4] = { f2bf(O[dt][0]), f2bf(O[dt][1]),
                       f2bf(O[dt][2]), f2bf(O[dt][3]) };
        *(u64*)(Ob + dt*16 + quad*4) = *(u64*)pk4;
    }
    lsum += __shfl_xor(lsum,16);
    lsum += __shfl_xor(lsum,32);
    if (lane < 16)
        lpart[((size_t)ks*16 + bh)*Sq + q0 + w*16 + l16] = lsum;
}

// ---------------------------------------------------------------------------
// K3: combine 4 bf16 split-K partials -> bf16 A-tile; out-proj (swapped MFMA)
// + residual + LN2 + (x2 + h2) -> d_out. 8 rows/block, 1024 blocks.
// ---------------------------------------------------------------------------
__global__ __launch_bounds__(256) void k3_gemm_ln(
    const u16* __restrict__ Opart, const float* __restrict__ lpart,
    const u16* __restrict__ wTo,
    const float* __restrict__ bo, const float* __restrict__ x1,
    const float* __restrict__ g2, const float* __restrict__ be2,
    float* __restrict__ out)
{
    const int tid  = threadIdx.x;
    const int w    = tid >> 6;
    const int lane = tid & 63;
    const int l16  = lane & 15;
    const int quad = lane >> 4;
    const int r0   = blockIdx.x * 8;
    const int b    = r0 >> 11;
    const int s0   = r0 & (Sq-1);
    const int cb   = w * 64;
    const int c4   = cb + quad*4;

    __shared__ u16 Ats[16][264];
    __shared__ float red[2][16][4];
    __shared__ float linv[4][8];

    const size_t LS = (size_t)16*Sq;
    if (tid < 32){
        int h = tid >> 3, r = tid & 7;
        size_t li = ((size_t)(b*Hh + h))*Sq + s0 + r;
        linv[h][r] = 1.f / (lpart[li] + lpart[LS + li]
                          + lpart[2*LS + li] + lpart[3*LS + li]);
    }
    // zero fragment region of unused rows 8-15
    {
        int row8 = 8 + (tid >> 5), col8 = (tid & 31)*8;
        *(u64*)&Ats[row8][col8] = 0;
    }
    __syncthreads();

    const size_t SPLIT = (size_t)16*Sq*HDh;
    #pragma unroll
    for (int i=0;i<2;++i){
        int idx = i*256 + tid;                 // 512 items: h x row x c
        int h = idx >> 7, rem = idx & 127, row = rem >> 4, c = rem & 15;
        size_t base = (((size_t)(b*Hh + h))*Sq + s0 + row)*HDh + c*4;
        u64 p0 = *(const u64*)(Opart + base);
        u64 p1 = *(const u64*)(Opart + SPLIT + base);
        u64 p2 = *(const u64*)(Opart + 2*SPLIT + base);
        u64 p3 = *(const u64*)(Opart + 3*SPLIT + base);
        float li = linv[h][row];
        u16 pk[4];
        #pragma unroll
        for (int j=0;j<4;++j){
            float v = bf2f((u32)((p0 >> (16*j)) & 0xffffu))
                    + bf2f((u32)((p1 >> (16*j)) & 0xffffu))
                    + bf2f((u32)((p2 >> (16*j)) & 0xffffu))
                    + bf2f((u32)((p3 >> (16*j)) & 0xffffu));
            pk[j] = f2bf(v*li);
        }
        *(u64*)&Ats[row][h*64 + c*4] = *(u64*)pk;
    }
    __syncthreads();

    frag_cd acc[4];
    #pragma unroll
    for (int nt=0;nt<4;++nt){
        float4 b4 = *(const float4*)&bo[c4 + nt*16];
        acc[nt] = (frag_cd){b4.x, b4.y, b4.z, b4.w};
    }
    #pragma unroll
    for (int kc=0;kc<8;++kc){
        frag_ab aa = *(frag_ab*)&Ats[l16][kc*32 + quad*8];
        #pragma unroll
        for (int nt=0;nt<4;++nt){
            frag_ab wf = *(const frag_ab*)&wTo[(size_t)(cb+nt*16+l16)*Dd + kc*32 + quad*8];
            acc[nt] = __builtin_amdgcn_mfma_f32_16x16x32_bf16(wf, aa, acc[nt], 0,0,0);
        }
    }

    // x2 = proj + x1 ; LN partials (rows 0-7 real)
    const int lr = l16 & 7;                    // clamped row for loads
    float s=0.f, q=0.f;
    #pragma unroll
    for (int nt=0;nt<4;++nt){
        float4 r4 = *(const float4*)&x1[(size_t)(r0+lr)*Dd + c4 + nt*16];
        acc[nt][0] += r4.x; acc[nt][1] += r4.y;
        acc[nt][2] += r4.z; acc[nt][3] += r4.w;
        s += acc[nt][0]+acc[nt][1]+acc[nt][2]+acc[nt][3];
        q += acc[nt][0]*acc[nt][0] + acc[nt][1]*acc[nt][1]
           + acc[nt][2]*acc[nt][2] + acc[nt][3]*acc[nt][3];
    }
    s += __shfl_xor(s,16); q += __shfl_xor(q,16);
    s += __shfl_xor(s,32); q += __shfl_xor(q,32);
    if (lane < 8){ red[0][l16][w]=s; red[1][l16][w]=q; }
    __syncthreads();

    {
        float mu = (red[0][l16][0]+red[0][l16][1]+red[0][l16][2]+red[0][l16][3])*(1.f/Dd);
        float ms = (red[1][l16][0]+red[1][l16][1]+red[1][l16][2]+red[1][l16][3])*(1.f/Dd);
        float rstd = rsqrtf(ms - mu*mu + EPSf);
        if (l16 < 8){
            #pragma unroll
            for (int nt=0;nt<4;++nt){
                float4 g4 = *(const float4*)&g2[c4 + nt*16];
                float4 e4 = *(const float4*)&be2[c4 + nt*16];
                float4 o4;
                o4.x = acc[nt][0] + (acc[nt][0]-mu)*rstd*g4.x + e4.x;
                o4.y = acc[nt][1] + (acc[nt][1]-mu)*rstd*g4.y + e4.y;
                o4.z = acc[nt][2] + (acc[nt][2]-mu)*rstd*g4.z + e4.z;
                o4.w = acc[nt][3] + (acc[nt][3]-mu)*rstd*g4.w + e4.w;
                *(float4*)&out[(size_t)(r0+l16)*Dd + c4 + nt*16] = o4;
            }
        }
    }
}

// ---------------------------------------------------------------------------
extern "C" void kernel_launch(void* const* d_in, const int* in_sizes, int n_in,
                              void* d_out, int out_size, void* d_ws, size_t ws_size,
                              hipStream_t stream)
{
    const float* x    = (const float*)d_in[0];
    const int*   mask = (const int*)  d_in[1];
    const float* w_in = (const float*)d_in[2];
    const float* b_in = (const float*)d_in[3];
    const float* g1   = (const float*)d_in[4];
    const float* be1  = (const float*)d_in[5];
    const float* wq   = (const float*)d_in[6];
    const float* bq   = (const float*)d_in[7];
    const float* wk   = (const float*)d_in[8];
    const float* bk   = (const float*)d_in[9];
    const float* wv   = (const float*)d_in[10];
    const float* bv   = (const float*)d_in[11];
    const float* wo   = (const float*)d_in[12];
    const float* bo   = (const float*)d_in[13];
    const float* g2   = (const float*)d_in[14];
    const float* be2  = (const float*)d_in[15];
    // inputs 16..21 (gating / experts) provably contribute 0.0 to the output.

    float* out = (float*)d_out;
    char*  wsb = (char*)d_ws;

    float* x1    = (float*)(wsb);                   // 8 MB fp32
    float* tab   = (float*)(wsb + ( 8u<<20));       // 512 KB RoPE table
    u16*   qro   = (u16*)(wsb + (12u<<20));
    u16*   kro   = (u16*)(wsb + (16u<<20));
    u16*   vto   = (u16*)(wsb + (20u<<20));         // [B,H,64,S]
    u16*   Opart = (u16*)(wsb + (24u<<20));         // [4][16][S][64] bf16 = 16 MB
    float* lpart = (float*)(wsb + (40u<<20));       // [4][16][S] fp32 = 512 KB
    u16*   wT    = (u16*)(wsb + (40u<<20) + (768u<<10)); // 5 x 256x256 bf16

    k0_prep<<<336, 256, 0, stream>>>(w_in, wq, wk, wv, wo, wT, tab);
    k1_fused<<<NROWS/8, 256, 0, stream>>>(
        x, tab, wT, wT + Dd*Dd, wT + 2*Dd*Dd, wT + 3*Dd*Dd,
        b_in, g1, be1, bq, bk, bv, x1, qro, kro, vto);
    k2_attn<<<dim3(Sq/128, Bb*Hh, 4), 512, 0, stream>>>(qro, kro, vto, mask, Opart, lpart);
    k3_gemm_ln<<<NROWS/8, 256, 0, stream>>>(Opart, lpart, wT + 4*Dd*Dd,
                                            bo, x1, g2, be2, out);
}

// Round 10
// 178.222 us; speedup vs baseline: 1.2718x; 1.2718x over previous
//
#include <hip/hip_runtime.h>
#include <cstddef>

#define Bb    4
#define Sq    2048
#define Dd    256
#define Hh    4
#define HDh   64
#define NROWS (Bb*Sq)     // 8192
#define EPSf  1e-5f

typedef unsigned short u16;
typedef unsigned int   u32;
typedef unsigned long long u64;
typedef __attribute__((ext_vector_type(8))) short  frag_ab;  // 8 bf16 (4 VGPRs)
typedef __attribute__((ext_vector_type(4))) float  frag_cd;  // 4 fp32

__device__ __forceinline__ u16 f2bf(float f){
    union { float f; u32 u; } v; v.f = f;
    u32 r = v.u + 0x7fffu + ((v.u >> 16) & 1u);   // RNE
    return (u16)(r >> 16);
}
__device__ __forceinline__ u16 f2bf_trunc(float f){
    union { float f; u32 u; } v; v.f = f;
    return (u16)(v.u >> 16);                      // 1-op truncation
}
__device__ __forceinline__ float bf2f(u32 u){
    union { u32 u; float f; } v; v.u = u << 16; return v.f;
}

// ---------------------------------------------------------------------------
// K0: prep. blocks 0..79: transpose+convert 5 weights -> wT[n][k] bf16.
//     blocks 80..335: RoPE table tab[s][0..31]=cos, [32..63]=sin.
// ---------------------------------------------------------------------------
__global__ __launch_bounds__(256) void k0_prep(
    const float* __restrict__ w_in, const float* __restrict__ wq,
    const float* __restrict__ wk,   const float* __restrict__ wv,
    const float* __restrict__ wo,
    u16* __restrict__ wT, float* __restrict__ tab)
{
    const int bid = blockIdx.x, tid = threadIdx.x;
    if (bid < 80){
        __shared__ float T[64][65];
        const int wsel = bid >> 4, tile = bid & 15;
        const int k0 = (tile >> 2) * 64, n0 = (tile & 3) * 64;
        const float* src = wsel==0 ? w_in : wsel==1 ? wq : wsel==2 ? wk
                         : wsel==3 ? wv : wo;
        #pragma unroll
        for (int i=0;i<16;++i){
            int idx = i*256 + tid, k = idx>>6, n = idx&63;
            T[k][n] = src[(size_t)(k0+k)*Dd + n0 + n];
        }
        __syncthreads();
        u16* dst = wT + (size_t)wsel*Dd*Dd;
        #pragma unroll
        for (int i=0;i<16;++i){
            int idx = i*256 + tid, n = idx>>6, k = idx&63;
            dst[(size_t)(n0+n)*Dd + k0 + k] = f2bf(T[k][n]);
        }
    } else {
        int s = (bid-80)*8 + (tid>>5);
        int p = tid & 31;
        float invf = exp2f(-(float)p * (13.287712379549449f/32.f)); // log2(1e4)/32
        float sn, cs; sincosf((float)s * invf, &sn, &cs);
        tab[(size_t)s*64 + p]      = cs;
        tab[(size_t)s*64 + 32 + p] = sn;
    }
}

// ---------------------------------------------------------------------------
// K1 fused: 32 rows/block, 256 blocks (1/CU). Each weight fragment load
// feeds TWO 16-row A-fragments -> per-CU weight traffic halved vs 16-row
// version (k1 is throughput-bound on the L2->CU weight path, ~11.5 B/cyc/CU).
// Swapped operands: lane holds token=(rg*16+l16) x 16 contiguous cols.
// ---------------------------------------------------------------------------
__global__ __launch_bounds__(256) void k1_fused(
    const float* __restrict__ x,  const float* __restrict__ tab,
    const u16* __restrict__ wTin, const u16* __restrict__ wTq,
    const u16* __restrict__ wTk,  const u16* __restrict__ wTv,
    const float* __restrict__ b_in, const float* __restrict__ g1,
    const float* __restrict__ be1,  const float* __restrict__ bq,
    const float* __restrict__ bk,   const float* __restrict__ bv,
    float* __restrict__ x1, u16* __restrict__ qro,
    u16* __restrict__ kro,  u16* __restrict__ vto)
{
    const int tid  = threadIdx.x;
    const int w    = tid >> 6;
    const int lane = tid & 63;
    const int l16  = lane & 15;
    const int quad = lane >> 4;
    const int r0   = blockIdx.x * 32;
    const int b    = r0 >> 11;
    const int s0   = r0 & (Sq-1);
    const int cb   = w * 64;              // wave's column base
    const int c4   = cb + quad*4;         // lane's first column (per nt: +nt*16)

    __shared__ u16 Xs[32][264];
    __shared__ u16 Hs[32][264];
    __shared__ u16 Os[32][264];
    __shared__ float red[2][32][4];

    // stage x tile: 32 rows, fp32->bf16
    #pragma unroll
    for (int i=0;i<8;++i){
        int f = i*256 + tid;
        int row = f>>6, cc = f&63;
        float4 v4 = *(const float4*)(x + (size_t)(r0+row)*Dd + cc*4);
        u16 pk4[4] = { f2bf(v4.x), f2bf(v4.y), f2bf(v4.z), f2bf(v4.w) };
        *(u64*)&Xs[row][cc*4] = *(u64*)pk4;
    }
    __syncthreads();

    // in-proj: acc[rg][nt] = y[token=rg*16+l16][c4+nt*16 .. +3]
    frag_cd acc[2][4];
    #pragma unroll
    for (int nt=0;nt<4;++nt){
        float4 b4 = *(const float4*)&b_in[c4 + nt*16];
        acc[0][nt] = (frag_cd){b4.x, b4.y, b4.z, b4.w};
        acc[1][nt] = acc[0][nt];
    }
    #pragma unroll
    for (int kc=0;kc<8;++kc){
        frag_ab xa0 = *(frag_ab*)&Xs[l16][kc*32 + quad*8];
        frag_ab xa1 = *(frag_ab*)&Xs[16+l16][kc*32 + quad*8];
        #pragma unroll
        for (int nt=0;nt<4;++nt){
            frag_ab wf = *(const frag_ab*)&wTin[(size_t)(cb+nt*16+l16)*Dd + kc*32 + quad*8];
            acc[0][nt] = __builtin_amdgcn_mfma_f32_16x16x32_bf16(wf, xa0, acc[0][nt], 0,0,0);
            acc[1][nt] = __builtin_amdgcn_mfma_f32_16x16x32_bf16(wf, xa1, acc[1][nt], 0,0,0);
        }
    }

    // x1 store (float4) + LN1 partial sums, per row-group
    #pragma unroll
    for (int rg=0;rg<2;++rg){
        float s=0.f, q=0.f;
        #pragma unroll
        for (int nt=0;nt<4;++nt){
            float4 v4 = make_float4(acc[rg][nt][0], acc[rg][nt][1],
                                    acc[rg][nt][2], acc[rg][nt][3]);
            *(float4*)&x1[(size_t)(r0+rg*16+l16)*Dd + c4 + nt*16] = v4;
            s += v4.x+v4.y+v4.z+v4.w;
            q += v4.x*v4.x + v4.y*v4.y + v4.z*v4.z + v4.w*v4.w;
        }
        s += __shfl_xor(s,16); q += __shfl_xor(q,16);
        s += __shfl_xor(s,32); q += __shfl_xor(q,32);
        if (lane < 16){ red[0][rg*16+l16][w]=s; red[1][rg*16+l16][w]=q; }
    }
    __syncthreads();

    #pragma unroll
    for (int rg=0;rg<2;++rg){
        int row = rg*16 + l16;
        float mu = (red[0][row][0]+red[0][row][1]+red[0][row][2]+red[0][row][3])*(1.f/Dd);
        float ms = (red[1][row][0]+red[1][row][1]+red[1][row][2]+red[1][row][3])*(1.f/Dd);
        float rstd = rsqrtf(ms - mu*mu + EPSf);
        #pragma unroll
        for (int nt=0;nt<4;++nt){
            float4 g4 = *(const float4*)&g1[c4 + nt*16];
            float4 e4 = *(const float4*)&be1[c4 + nt*16];
            u16 pk4[4] = { f2bf((acc[rg][nt][0]-mu)*rstd*g4.x + e4.x),
                           f2bf((acc[rg][nt][1]-mu)*rstd*g4.y + e4.y),
                           f2bf((acc[rg][nt][2]-mu)*rstd*g4.z + e4.z),
                           f2bf((acc[rg][nt][3]-mu)*rstd*g4.w + e4.w) };
            *(u64*)&Hs[row][c4 + nt*16] = *(u64*)pk4;
        }
    }
    __syncthreads();

    const u16*   wps[3] = { wTq, wTk, wTv };
    const float* bps[3] = { bq, bk, bv };
    #pragma unroll
    for (int tt=0; tt<3; ++tt){
        frag_cd a2[2][4];
        #pragma unroll
        for (int nt=0;nt<4;++nt){
            float4 b4 = *(const float4*)&bps[tt][c4 + nt*16];
            a2[0][nt] = (frag_cd){b4.x, b4.y, b4.z, b4.w};
            a2[1][nt] = a2[0][nt];
        }
        #pragma unroll
        for (int kc=0;kc<8;++kc){
            frag_ab ha0 = *(frag_ab*)&Hs[l16][kc*32 + quad*8];
            frag_ab ha1 = *(frag_ab*)&Hs[16+l16][kc*32 + quad*8];
            #pragma unroll
            for (int nt=0;nt<4;++nt){
                frag_ab wf = *(const frag_ab*)&wps[tt][(size_t)(cb+nt*16+l16)*Dd + kc*32 + quad*8];
                a2[0][nt] = __builtin_amdgcn_mfma_f32_16x16x32_bf16(wf, ha0, a2[0][nt], 0,0,0);
                a2[1][nt] = __builtin_amdgcn_mfma_f32_16x16x32_bf16(wf, ha1, a2[1][nt], 0,0,0);
            }
        }
        #pragma unroll
        for (int rg=0;rg<2;++rg)
            #pragma unroll
            for (int nt=0;nt<4;++nt){
                u16 pk4[4] = { f2bf(a2[rg][nt][0]), f2bf(a2[rg][nt][1]),
                               f2bf(a2[rg][nt][2]), f2bf(a2[rg][nt][3]) };
                *(u64*)&Os[rg*16+l16][c4 + nt*16] = *(u64*)pk4;
            }
        __syncthreads();

        if (tt < 2){
            // RoPE via table: 2 row-groups x (row 0-15, head, p-chunk of 8)
            #pragma unroll
            for (int rg=0;rg<2;++rg){
                const int row  = rg*16 + (tid >> 4);
                const int head = (tid >> 2) & 3;
                const int pq   = tid & 3;
                const int sidx = s0 + row;
                const float* tb = tab + (size_t)sidx*64;
                float4 c0 = *(const float4*)(tb + pq*8);
                float4 c1 = *(const float4*)(tb + pq*8 + 4);
                float4 sn0 = *(const float4*)(tb + 32 + pq*8);
                float4 sn1 = *(const float4*)(tb + 32 + pq*8 + 4);
                const float cA[8] = {c0.x,c0.y,c0.z,c0.w,c1.x,c1.y,c1.z,c1.w};
                const float sA[8] = {sn0.x,sn0.y,sn0.z,sn0.w,sn1.x,sn1.y,sn1.z,sn1.w};
                u16* dst = (tt==0 ? qro : kro) + ((size_t)(b*Hh+head)*Sq + sidx)*HDh;
                u16 lo[8], hi[8];
                #pragma unroll
                for (int j=0;j<8;++j){
                    int p = pq*8 + j;
                    u32 pr = *(const u32*)&Os[row][head*64 + 2*p];
                    float t0 = bf2f(pr & 0xffffu), t1 = bf2f(pr >> 16);
                    lo[j] = f2bf(t0*cA[j] - t1*sA[j]);
                    hi[j] = f2bf(t1*cA[j] + t0*sA[j]);
                }
                *(float4*)(dst + pq*8)      = *(float4*)lo;
                *(float4*)(dst + 32 + pq*8) = *(float4*)hi;
            }
        } else {
            // V transpose: (head, d); 16 tokens/row-group -> 2 float4 stores
            const int head = tid >> 6, d = lane;
            #pragma unroll
            for (int rg=0;rg<2;++rg){
                u16 pk[16];
                #pragma unroll
                for (int j=0;j<16;++j) pk[j] = Os[rg*16+j][head*64 + d];
                u16* dst = vto + ((size_t)(b*Hh+head)*HDh + d)*Sq + s0 + rg*16;
                *(float4*)dst     = *(float4*)pk;
                *(float4*)(dst+8) = *(float4*)&pk[8];
            }
        }
        __syncthreads();
    }
}

// ---------------------------------------------------------------------------
// K2: bf16 MFMA flash attention. 128-query blocks (8 waves, 512 thr),
// split-K x4 -> 1024 blocks = 4/CU = 32 waves/CU. Q fragments direct from
// global; K/V staged in LDS. Fixed-max softmax; bf16 O partials. (round-8)
// ---------------------------------------------------------------------------
__global__ __launch_bounds__(512) void k2_attn(
    const u16* __restrict__ qr, const u16* __restrict__ kr,
    const u16* __restrict__ vt, const int* __restrict__ mask,
    u16* __restrict__ Opart, float* __restrict__ lpart)
{
    const int tid = threadIdx.x;
    const int w   = tid >> 6;          // 0..7
    const int lane= tid & 63;
    const int l16 = lane & 15;
    const int quad= lane >> 4;
    const int qt  = blockIdx.x;        // 0..15
    const int bh  = blockIdx.y;        // 0..15
    const int ks  = blockIdx.z;        // 0..3 split over keys (512 each)
    const int b   = bh >> 2;
    const int q0  = qt * 128;

    __shared__ u16 Ks [64][72];
    __shared__ u16 Vts[64][72];
    __shared__ u16 Ps [8][16][72];

    const u16* qg = qr + ((size_t)bh*Sq + q0 + w*16 + l16)*HDh;
    frag_ab qf0 = *(const frag_ab*)(qg + quad*8);
    frag_ab qf1 = *(const frag_ab*)(qg + quad*8 + 32);

    const float mf2 = (mask[(size_t)b*Sq + q0 + w*16 + l16] != 0)
                    ? 0.125f*1.44269504f : 0.f;

    float lsum = 0.f;
    frag_cd O[4];
    #pragma unroll
    for (int d=0; d<4; ++d) O[d] = (frag_cd){0.f,0.f,0.f,0.f};

    const u16* kg0 = kr + ((size_t)bh*Sq + ks*512)*HDh;
    const u16* vg0 = vt + (size_t)bh*HDh*Sq + ks*512;

    const int srow = tid >> 3, spart = tid & 7;

    for (int kt=0; kt<8; ++kt){
        __syncthreads();
        const u16* kg = kg0 + (size_t)kt*64*HDh;
        const u16* vg = vg0 + kt*64;
        *(float4*)&Ks [srow][spart*8] = *(const float4*)(kg + srow*HDh + spart*8);
        *(float4*)&Vts[srow][spart*8] = *(const float4*)(vg + (size_t)srow*Sq + spart*8);
        __syncthreads();

        frag_cd sc[4];
        #pragma unroll
        for (int t=0;t<4;++t){
            frag_ab kf0 = *(frag_ab*)&Ks[t*16 + l16][quad*8];
            frag_ab kf1 = *(frag_ab*)&Ks[t*16 + l16][quad*8 + 32];
            frag_cd z = (frag_cd){0.f,0.f,0.f,0.f};
            z = __builtin_amdgcn_mfma_f32_16x16x32_bf16(kf0, qf0, z, 0,0,0);
            z = __builtin_amdgcn_mfma_f32_16x16x32_bf16(kf1, qf1, z, 0,0,0);
            sc[t] = z;
        }

        #pragma unroll
        for (int t=0;t<4;++t){
            float p0 = exp2f(sc[t][0]*mf2);
            float p1 = exp2f(sc[t][1]*mf2);
            float p2 = exp2f(sc[t][2]*mf2);
            float p3 = exp2f(sc[t][3]*mf2);
            lsum += p0+p1+p2+p3;
            u16 pk4[4] = { f2bf_trunc(p0), f2bf_trunc(p1),
                           f2bf_trunc(p2), f2bf_trunc(p3) };
            *(u64*)&Ps[w][l16][t*16 + quad*4] = *(u64*)pk4;
        }

        frag_ab pf0 = *(frag_ab*)&Ps[w][l16][quad*8];
        frag_ab pf1 = *(frag_ab*)&Ps[w][l16][quad*8 + 32];

        #pragma unroll
        for (int d=0; d<4; ++d){
            frag_ab vf0 = *(frag_ab*)&Vts[d*16 + l16][quad*8];
            frag_ab vf1 = *(frag_ab*)&Vts[d*16 + l16][quad*8 + 32];
            O[d] = __builtin_amdgcn_mfma_f32_16x16x32_bf16(vf0, pf0, O[d], 0,0,0);
            O[d] = __builtin_amdgcn_mfma_f32_16x16x32_bf16(vf1, pf1, O[d], 0,0,0);
        }
    }

    u16* Ob = Opart + (((size_t)ks*16 + bh)*Sq + q0 + w*16 + l16)*HDh;
    #pragma unroll
    for (int dt=0; dt<4; ++dt){
        u16 pk4[4] = { f2bf(O[dt][0]), f2bf(O[dt][1]),
                       f2bf(O[dt][2]), f2bf(O[dt][3]) };
        *(u64*)(Ob + dt*16 + quad*4) = *(u64*)pk4;
    }
    lsum += __shfl_xor(lsum,16);
    lsum += __shfl_xor(lsum,32);
    if (lane < 16)
        lpart[((size_t)ks*16 + bh)*Sq + q0 + w*16 + l16] = lsum;
}

// ---------------------------------------------------------------------------
// K3: combine 4 bf16 split-K partials -> bf16 A-tile; out-proj (swapped MFMA,
// weight frag feeds 2 row-fragments) + residual + LN2 + (x2+h2) -> d_out.
// 32 rows/block, 256 blocks.
// ---------------------------------------------------------------------------
__global__ __launch_bounds__(256) void k3_gemm_ln(
    const u16* __restrict__ Opart, const float* __restrict__ lpart,
    const u16* __restrict__ wTo,
    const float* __restrict__ bo, const float* __restrict__ x1,
    const float* __restrict__ g2, const float* __restrict__ be2,
    float* __restrict__ out)
{
    const int tid  = threadIdx.x;
    const int w    = tid >> 6;
    const int lane = tid & 63;
    const int l16  = lane & 15;
    const int quad = lane >> 4;
    const int r0   = blockIdx.x * 32;
    const int b    = r0 >> 11;
    const int s0   = r0 & (Sq-1);
    const int cb   = w * 64;
    const int c4   = cb + quad*4;

    __shared__ u16 Ats[32][264];
    __shared__ float red[2][32][4];
    __shared__ float linv[4][32];

    const size_t LS = (size_t)16*Sq;
    if (tid < 128){
        int h = tid >> 5, r = tid & 31;
        size_t li = ((size_t)(b*Hh + h))*Sq + s0 + r;
        linv[h][r] = 1.f / (lpart[li] + lpart[LS + li]
                          + lpart[2*LS + li] + lpart[3*LS + li]);
    }
    __syncthreads();

    const size_t SPLIT = (size_t)16*Sq*HDh;
    #pragma unroll
    for (int i=0;i<8;++i){
        int idx = i*256 + tid;                 // 2048 items: h x row x c
        int h = idx >> 9, rem = idx & 511, row = rem >> 4, c = rem & 15;
        size_t base = (((size_t)(b*Hh + h))*Sq + s0 + row)*HDh + c*4;
        u64 p0 = *(const u64*)(Opart + base);
        u64 p1 = *(const u64*)(Opart + SPLIT + base);
        u64 p2 = *(const u64*)(Opart + 2*SPLIT + base);
        u64 p3 = *(const u64*)(Opart + 3*SPLIT + base);
        float li = linv[h][row];
        u16 pk[4];
        #pragma unroll
        for (int j=0;j<4;++j){
            float v = bf2f((u32)((p0 >> (16*j)) & 0xffffu))
                    + bf2f((u32)((p1 >> (16*j)) & 0xffffu))
                    + bf2f((u32)((p2 >> (16*j)) & 0xffffu))
                    + bf2f((u32)((p3 >> (16*j)) & 0xffffu));
            pk[j] = f2bf(v*li);
        }
        *(u64*)&Ats[row][h*64 + c*4] = *(u64*)pk;
    }
    __syncthreads();

    frag_cd acc[2][4];
    #pragma unroll
    for (int nt=0;nt<4;++nt){
        float4 b4 = *(const float4*)&bo[c4 + nt*16];
        acc[0][nt] = (frag_cd){b4.x, b4.y, b4.z, b4.w};
        acc[1][nt] = acc[0][nt];
    }
    #pragma unroll
    for (int kc=0;kc<8;++kc){
        frag_ab aa0 = *(frag_ab*)&Ats[l16][kc*32 + quad*8];
        frag_ab aa1 = *(frag_ab*)&Ats[16+l16][kc*32 + quad*8];
        #pragma unroll
        for (int nt=0;nt<4;++nt){
            frag_ab wf = *(const frag_ab*)&wTo[(size_t)(cb+nt*16+l16)*Dd + kc*32 + quad*8];
            acc[0][nt] = __builtin_amdgcn_mfma_f32_16x16x32_bf16(wf, aa0, acc[0][nt], 0,0,0);
            acc[1][nt] = __builtin_amdgcn_mfma_f32_16x16x32_bf16(wf, aa1, acc[1][nt], 0,0,0);
        }
    }

    // x2 = proj + x1 ; LN partials per row-group
    #pragma unroll
    for (int rg=0;rg<2;++rg){
        float s=0.f, q=0.f;
        #pragma unroll
        for (int nt=0;nt<4;++nt){
            float4 r4 = *(const float4*)&x1[(size_t)(r0+rg*16+l16)*Dd + c4 + nt*16];
            acc[rg][nt][0] += r4.x; acc[rg][nt][1] += r4.y;
            acc[rg][nt][2] += r4.z; acc[rg][nt][3] += r4.w;
            s += acc[rg][nt][0]+acc[rg][nt][1]+acc[rg][nt][2]+acc[rg][nt][3];
            q += acc[rg][nt][0]*acc[rg][nt][0] + acc[rg][nt][1]*acc[rg][nt][1]
               + acc[rg][nt][2]*acc[rg][nt][2] + acc[rg][nt][3]*acc[rg][nt][3];
        }
        s += __shfl_xor(s,16); q += __shfl_xor(q,16);
        s += __shfl_xor(s,32); q += __shfl_xor(q,32);
        if (lane < 16){ red[0][rg*16+l16][w]=s; red[1][rg*16+l16][w]=q; }
    }
    __syncthreads();

    #pragma unroll
    for (int rg=0;rg<2;++rg){
        int row = rg*16 + l16;
        float mu = (red[0][row][0]+red[0][row][1]+red[0][row][2]+red[0][row][3])*(1.f/Dd);
        float ms = (red[1][row][0]+red[1][row][1]+red[1][row][2]+red[1][row][3])*(1.f/Dd);
        float rstd = rsqrtf(ms - mu*mu + EPSf);
        #pragma unroll
        for (int nt=0;nt<4;++nt){
            float4 g4 = *(const float4*)&g2[c4 + nt*16];
            float4 e4 = *(const float4*)&be2[c4 + nt*16];
            float4 o4;
            o4.x = acc[rg][nt][0] + (acc[rg][nt][0]-mu)*rstd*g4.x + e4.x;
            o4.y = acc[rg][nt][1] + (acc[rg][nt][1]-mu)*rstd*g4.y + e4.y;
            o4.z = acc[rg][nt][2] + (acc[rg][nt][2]-mu)*rstd*g4.z + e4.z;
            o4.w = acc[rg][nt][3] + (acc[rg][nt][3]-mu)*rstd*g4.w + e4.w;
            *(float4*)&out[(size_t)(r0+row)*Dd + c4 + nt*16] = o4;
        }
    }
}

// ---------------------------------------------------------------------------
extern "C" void kernel_launch(void* const* d_in, const int* in_sizes, int n_in,
                              void* d_out, int out_size, void* d_ws, size_t ws_size,
                              hipStream_t stream)
{
    const float* x    = (const float*)d_in[0];
    const int*   mask = (const int*)  d_in[1];
    const float* w_in = (const float*)d_in[2];
    const float* b_in = (const float*)d_in[3];
    const float* g1   = (const float*)d_in[4];
    const float* be1  = (const float*)d_in[5];
    const float* wq   = (const float*)d_in[6];
    const float* bq   = (const float*)d_in[7];
    const float* wk   = (const float*)d_in[8];
    const float* bk   = (const float*)d_in[9];
    const float* wv   = (const float*)d_in[10];
    const float* bv   = (const float*)d_in[11];
    const float* wo   = (const float*)d_in[12];
    const float* bo   = (const float*)d_in[13];
    const float* g2   = (const float*)d_in[14];
    const float* be2  = (const float*)d_in[15];
    // inputs 16..21 (gating / experts) provably contribute 0.0 to the output.

    float* out = (float*)d_out;
    char*  wsb = (char*)d_ws;

    float* x1    = (float*)(wsb);                   // 8 MB fp32
    float* tab   = (float*)(wsb + ( 8u<<20));       // 512 KB RoPE table
    u16*   qro   = (u16*)(wsb + (12u<<20));
    u16*   kro   = (u16*)(wsb + (16u<<20));
    u16*   vto   = (u16*)(wsb + (20u<<20));         // [B,H,64,S]
    u16*   Opart = (u16*)(wsb + (24u<<20));         // [4][16][S][64] bf16 = 16 MB
    float* lpart = (float*)(wsb + (40u<<20));       // [4][16][S] fp32 = 512 KB
    u16*   wT    = (u16*)(wsb + (40u<<20) + (768u<<10)); // 5 x 256x256 bf16

    k0_prep<<<336, 256, 0, stream>>>(w_in, wq, wk, wv, wo, wT, tab);
    k1_fused<<<NROWS/32, 256, 0, stream>>>(
        x, tab, wT, wT + Dd*Dd, wT + 2*Dd*Dd, wT + 3*Dd*Dd,
        b_in, g1, be1, bq, bk, bv, x1, qro, kro, vto);
    k2_attn<<<dim3(Sq/128, Bb*Hh, 4), 512, 0, stream>>>(qro, kro, vto, mask, Opart, lpart);
    k3_gemm_ln<<<NROWS/32, 256, 0, stream>>>(Opart, lpart, wT + 4*Dd*Dd,
                                             bo, x1, g2, be2, out);
}

// Round 11
// 170.747 us; speedup vs baseline: 1.3275x; 1.0438x over previous
//
#include <hip/hip_runtime.h>
#include <cstddef>

#define Bb    4
#define Sq    2048
#define Dd    256
#define Hh    4
#define HDh   64
#define NROWS (Bb*Sq)     // 8192
#define EPSf  1e-5f

typedef unsigned short u16;
typedef unsigned int   u32;
typedef unsigned long long u64;
typedef __attribute__((ext_vector_type(8))) short  frag_ab;  // 8 bf16 (4 VGPRs)
typedef __attribute__((ext_vector_type(4))) float  frag_cd;  // 4 fp32

__device__ __forceinline__ u16 f2bf(float f){
    union { float f; u32 u; } v; v.f = f;
    u32 r = v.u + 0x7fffu + ((v.u >> 16) & 1u);   // RNE
    return (u16)(r >> 16);
}
__device__ __forceinline__ u16 f2bf_trunc(float f){
    union { float f; u32 u; } v; v.f = f;
    return (u16)(v.u >> 16);                      // 1-op truncation
}
__device__ __forceinline__ float bf2f(u32 u){
    union { u32 u; float f; } v; v.u = u << 16; return v.f;
}

// ---------------------------------------------------------------------------
// K0: prep. blocks 0..79: transpose+convert 5 weights -> wT[n][k] bf16
// (order: w_in, wq, wk, wv, wo — so wq|wk|wv form a contiguous 768x256).
//     blocks 80..335: RoPE table tab[s][0..31]=cos, [32..63]=sin.
// ---------------------------------------------------------------------------
__global__ __launch_bounds__(256) void k0_prep(
    const float* __restrict__ w_in, const float* __restrict__ wq,
    const float* __restrict__ wk,   const float* __restrict__ wv,
    const float* __restrict__ wo,
    u16* __restrict__ wT, float* __restrict__ tab)
{
    const int bid = blockIdx.x, tid = threadIdx.x;
    if (bid < 80){
        __shared__ float T[64][65];
        const int wsel = bid >> 4, tile = bid & 15;
        const int k0 = (tile >> 2) * 64, n0 = (tile & 3) * 64;
        const float* src = wsel==0 ? w_in : wsel==1 ? wq : wsel==2 ? wk
                         : wsel==3 ? wv : wo;
        #pragma unroll
        for (int i=0;i<16;++i){
            int idx = i*256 + tid, k = idx>>6, n = idx&63;
            T[k][n] = src[(size_t)(k0+k)*Dd + n0 + n];
        }
        __syncthreads();
        u16* dst = wT + (size_t)wsel*Dd*Dd;
        #pragma unroll
        for (int i=0;i<16;++i){
            int idx = i*256 + tid, n = idx>>6, k = idx&63;
            dst[(size_t)(n0+n)*Dd + k0 + k] = f2bf(T[k][n]);
        }
    } else {
        int s = (bid-80)*8 + (tid>>5);
        int p = tid & 31;
        float invf = exp2f(-(float)p * (13.287712379549449f/32.f)); // log2(1e4)/32
        float sn, cs; sincosf((float)s * invf, &sn, &cs);
        tab[(size_t)s*64 + p]      = cs;
        tab[(size_t)s*64 + 32 + p] = sn;
    }
}

// ---------------------------------------------------------------------------
// K1 fused: 32 rows/block, 512 threads (8 waves), 256 blocks (1/CU).
// Phase A: in-proj (wave owns 32 cols). Phase B: merged QKV GEMM over the
// contiguous wqkv [768x256] (wave owns 96 cols) — one phase, 48 independent
// weight loads, 96 MFMAs, minimal barriers. Epilogues: RoPE q, RoPE k, V^T.
// ---------------------------------------------------------------------------
__global__ __launch_bounds__(512) void k1_fused(
    const float* __restrict__ x,  const float* __restrict__ tab,
    const u16* __restrict__ wTin, const u16* __restrict__ wTqkv,
    const float* __restrict__ b_in, const float* __restrict__ g1,
    const float* __restrict__ be1,  const float* __restrict__ bq,
    const float* __restrict__ bk,   const float* __restrict__ bv,
    float* __restrict__ x1, u16* __restrict__ qro,
    u16* __restrict__ kro,  u16* __restrict__ vto)
{
    const int tid  = threadIdx.x;
    const int w    = tid >> 6;            // 0..7
    const int lane = tid & 63;
    const int l16  = lane & 15;
    const int quad = lane >> 4;
    const int r0   = blockIdx.x * 32;
    const int b    = r0 >> 11;
    const int s0   = r0 & (Sq-1);

    __shared__ u16 Xs[32][264];
    __shared__ u16 Hs[32][264];
    __shared__ u16 Os[32][776];           // 768 cols + pad
    __shared__ float red[2][32][8];

    // stage x tile: 32 rows x 256 cols, fp32->bf16 (2048 float4 / 512 thr)
    #pragma unroll
    for (int i=0;i<4;++i){
        int f = i*512 + tid;
        int row = f>>6, cc = f&63;
        float4 v4 = *(const float4*)(x + (size_t)(r0+row)*Dd + cc*4);
        u16 pk4[4] = { f2bf(v4.x), f2bf(v4.y), f2bf(v4.z), f2bf(v4.w) };
        *(u64*)&Xs[row][cc*4] = *(u64*)pk4;
    }
    __syncthreads();

    // ---- Phase A: in-proj, wave owns cols [w*32, w*32+32) ----
    const int cA = w*32 + quad*4;         // +nt*16
    frag_cd acc[2][2];
    #pragma unroll
    for (int nt=0;nt<2;++nt){
        float4 b4 = *(const float4*)&b_in[cA + nt*16];
        acc[0][nt] = (frag_cd){b4.x, b4.y, b4.z, b4.w};
        acc[1][nt] = acc[0][nt];
    }
    #pragma unroll
    for (int kc=0;kc<8;++kc){
        frag_ab xa0 = *(frag_ab*)&Xs[l16][kc*32 + quad*8];
        frag_ab xa1 = *(frag_ab*)&Xs[16+l16][kc*32 + quad*8];
        #pragma unroll
        for (int nt=0;nt<2;++nt){
            frag_ab wf = *(const frag_ab*)&wTin[(size_t)(w*32+nt*16+l16)*Dd + kc*32 + quad*8];
            acc[0][nt] = __builtin_amdgcn_mfma_f32_16x16x32_bf16(wf, xa0, acc[0][nt], 0,0,0);
            acc[1][nt] = __builtin_amdgcn_mfma_f32_16x16x32_bf16(wf, xa1, acc[1][nt], 0,0,0);
        }
    }

    // x1 store + LN partials
    #pragma unroll
    for (int rg=0;rg<2;++rg){
        float s=0.f, q=0.f;
        #pragma unroll
        for (int nt=0;nt<2;++nt){
            float4 v4 = make_float4(acc[rg][nt][0], acc[rg][nt][1],
                                    acc[rg][nt][2], acc[rg][nt][3]);
            *(float4*)&x1[(size_t)(r0+rg*16+l16)*Dd + cA + nt*16] = v4;
            s += v4.x+v4.y+v4.z+v4.w;
            q += v4.x*v4.x + v4.y*v4.y + v4.z*v4.z + v4.w*v4.w;
        }
        s += __shfl_xor(s,16); q += __shfl_xor(q,16);
        s += __shfl_xor(s,32); q += __shfl_xor(q,32);
        if (lane < 16){ red[0][rg*16+l16][w]=s; red[1][rg*16+l16][w]=q; }
    }
    __syncthreads();

    #pragma unroll
    for (int rg=0;rg<2;++rg){
        int row = rg*16 + l16;
        float s8=0.f, q8=0.f;
        #pragma unroll
        for (int j=0;j<8;++j){ s8 += red[0][row][j]; q8 += red[1][row][j]; }
        float mu = s8*(1.f/Dd), ms = q8*(1.f/Dd);
        float rstd = rsqrtf(ms - mu*mu + EPSf);
        #pragma unroll
        for (int nt=0;nt<2;++nt){
            float4 g4 = *(const float4*)&g1[cA + nt*16];
            float4 e4 = *(const float4*)&be1[cA + nt*16];
            u16 pk4[4] = { f2bf((acc[rg][nt][0]-mu)*rstd*g4.x + e4.x),
                           f2bf((acc[rg][nt][1]-mu)*rstd*g4.y + e4.y),
                           f2bf((acc[rg][nt][2]-mu)*rstd*g4.z + e4.z),
                           f2bf((acc[rg][nt][3]-mu)*rstd*g4.w + e4.w) };
            *(u64*)&Hs[rg*16+l16][cA + nt*16] = *(u64*)pk4;
        }
    }
    __syncthreads();

    // ---- Phase B: merged QKV, wave owns cols [w*96, w*96+96) of 768 ----
    frag_cd a2[2][6];
    #pragma unroll
    for (int nt=0;nt<6;++nt){
        int c0 = w*96 + nt*16;            // tile start, 16-aligned, one matrix
        const float* bp = (c0 < 256) ? bq : (c0 < 512 ? bk : bv);
        int cc = (c0 & 255) + quad*4;
        float4 b4 = *(const float4*)&bp[cc];
        a2[0][nt] = (frag_cd){b4.x, b4.y, b4.z, b4.w};
        a2[1][nt] = a2[0][nt];
    }
    #pragma unroll
    for (int kc=0;kc<8;++kc){
        frag_ab ha0 = *(frag_ab*)&Hs[l16][kc*32 + quad*8];
        frag_ab ha1 = *(frag_ab*)&Hs[16+l16][kc*32 + quad*8];
        #pragma unroll
        for (int nt=0;nt<6;++nt){
            frag_ab wf = *(const frag_ab*)&wTqkv[(size_t)(w*96+nt*16+l16)*Dd + kc*32 + quad*8];
            a2[0][nt] = __builtin_amdgcn_mfma_f32_16x16x32_bf16(wf, ha0, a2[0][nt], 0,0,0);
            a2[1][nt] = __builtin_amdgcn_mfma_f32_16x16x32_bf16(wf, ha1, a2[1][nt], 0,0,0);
        }
    }
    #pragma unroll
    for (int rg=0;rg<2;++rg)
        #pragma unroll
        for (int nt=0;nt<6;++nt){
            u16 pk4[4] = { f2bf(a2[rg][nt][0]), f2bf(a2[rg][nt][1]),
                           f2bf(a2[rg][nt][2]), f2bf(a2[rg][nt][3]) };
            *(u64*)&Os[rg*16+l16][w*96 + nt*16 + quad*4] = *(u64*)pk4;
        }
    __syncthreads();

    // ---- Epilogues (Os: q=0..255, k=256..511, v=512..767) ----
    {   // RoPE for q and k: thread -> (row 0-31, head, p-chunk of 8)
        const int row  = tid >> 4;
        const int head = (tid >> 2) & 3;
        const int pq   = tid & 3;
        const int sidx = s0 + row;
        const float* tb = tab + (size_t)sidx*64;
        float4 c0 = *(const float4*)(tb + pq*8);
        float4 c1 = *(const float4*)(tb + pq*8 + 4);
        float4 sn0 = *(const float4*)(tb + 32 + pq*8);
        float4 sn1 = *(const float4*)(tb + 32 + pq*8 + 4);
        const float cAr[8] = {c0.x,c0.y,c0.z,c0.w,c1.x,c1.y,c1.z,c1.w};
        const float sAr[8] = {sn0.x,sn0.y,sn0.z,sn0.w,sn1.x,sn1.y,sn1.z,sn1.w};
        #pragma unroll
        for (int tt=0; tt<2; ++tt){
            const int cbase = tt*256 + head*64;
            u16* dst = (tt==0 ? qro : kro) + ((size_t)(b*Hh+head)*Sq + sidx)*HDh;
            u16 lo[8], hi[8];
            #pragma unroll
            for (int j=0;j<8;++j){
                int p = pq*8 + j;
                u32 pr = *(const u32*)&Os[row][cbase + 2*p];
                float t0 = bf2f(pr & 0xffffu), t1 = bf2f(pr >> 16);
                lo[j] = f2bf(t0*cAr[j] - t1*sAr[j]);
                hi[j] = f2bf(t1*cAr[j] + t0*sAr[j]);
            }
            *(float4*)(dst + pq*8)      = *(float4*)lo;
            *(float4*)(dst + 32 + pq*8) = *(float4*)hi;
        }
    }
    {   // V^T: thread -> (head=tid>>7, d=(tid>>1)&63, rg=tid&1), 16 tokens
        const int head = tid >> 7, d = (tid >> 1) & 63, rg = tid & 1;
        u16 pk[16];
        #pragma unroll
        for (int j=0;j<16;++j) pk[j] = Os[rg*16+j][512 + head*64 + d];
        u16* dst = vto + ((size_t)(b*Hh+head)*HDh + d)*Sq + s0 + rg*16;
        *(float4*)dst     = *(float4*)pk;
        *(float4*)(dst+8) = *(float4*)&pk[8];
    }
}

// ---------------------------------------------------------------------------
// K2: bf16 MFMA flash attention. 128-query blocks (8 waves, 512 thr),
// split-K x4 -> 1024 blocks = 4/CU = 32 waves/CU. (round-8, known-good)
// ---------------------------------------------------------------------------
__global__ __launch_bounds__(512) void k2_attn(
    const u16* __restrict__ qr, const u16* __restrict__ kr,
    const u16* __restrict__ vt, const int* __restrict__ mask,
    u16* __restrict__ Opart, float* __restrict__ lpart)
{
    const int tid = threadIdx.x;
    const int w   = tid >> 6;          // 0..7
    const int lane= tid & 63;
    const int l16 = lane & 15;
    const int quad= lane >> 4;
    const int qt  = blockIdx.x;        // 0..15
    const int bh  = blockIdx.y;        // 0..15
    const int ks  = blockIdx.z;        // 0..3 split over keys (512 each)
    const int b   = bh >> 2;
    const int q0  = qt * 128;

    __shared__ u16 Ks [64][72];
    __shared__ u16 Vts[64][72];
    __shared__ u16 Ps [8][16][72];

    const u16* qg = qr + ((size_t)bh*Sq + q0 + w*16 + l16)*HDh;
    frag_ab qf0 = *(const frag_ab*)(qg + quad*8);
    frag_ab qf1 = *(const frag_ab*)(qg + quad*8 + 32);

    const float mf2 = (mask[(size_t)b*Sq + q0 + w*16 + l16] != 0)
                    ? 0.125f*1.44269504f : 0.f;

    float lsum = 0.f;
    frag_cd O[4];
    #pragma unroll
    for (int d=0; d<4; ++d) O[d] = (frag_cd){0.f,0.f,0.f,0.f};

    const u16* kg0 = kr + ((size_t)bh*Sq + ks*512)*HDh;
    const u16* vg0 = vt + (size_t)bh*HDh*Sq + ks*512;

    const int srow = tid >> 3, spart = tid & 7;

    for (int kt=0; kt<8; ++kt){
        __syncthreads();
        const u16* kg = kg0 + (size_t)kt*64*HDh;
        const u16* vg = vg0 + kt*64;
        *(float4*)&Ks [srow][spart*8] = *(const float4*)(kg + srow*HDh + spart*8);
        *(float4*)&Vts[srow][spart*8] = *(const float4*)(vg + (size_t)srow*Sq + spart*8);
        __syncthreads();

        frag_cd sc[4];
        #pragma unroll
        for (int t=0;t<4;++t){
            frag_ab kf0 = *(frag_ab*)&Ks[t*16 + l16][quad*8];
            frag_ab kf1 = *(frag_ab*)&Ks[t*16 + l16][quad*8 + 32];
            frag_cd z = (frag_cd){0.f,0.f,0.f,0.f};
            z = __builtin_amdgcn_mfma_f32_16x16x32_bf16(kf0, qf0, z, 0,0,0);
            z = __builtin_amdgcn_mfma_f32_16x16x32_bf16(kf1, qf1, z, 0,0,0);
            sc[t] = z;
        }

        #pragma unroll
        for (int t=0;t<4;++t){
            float p0 = exp2f(sc[t][0]*mf2);
            float p1 = exp2f(sc[t][1]*mf2);
            float p2 = exp2f(sc[t][2]*mf2);
            float p3 = exp2f(sc[t][3]*mf2);
            lsum += p0+p1+p2+p3;
            u16 pk4[4] = { f2bf_trunc(p0), f2bf_trunc(p1),
                           f2bf_trunc(p2), f2bf_trunc(p3) };
            *(u64*)&Ps[w][l16][t*16 + quad*4] = *(u64*)pk4;
        }

        frag_ab pf0 = *(frag_ab*)&Ps[w][l16][quad*8];
        frag_ab pf1 = *(frag_ab*)&Ps[w][l16][quad*8 + 32];

        #pragma unroll
        for (int d=0; d<4; ++d){
            frag_ab vf0 = *(frag_ab*)&Vts[d*16 + l16][quad*8];
            frag_ab vf1 = *(frag_ab*)&Vts[d*16 + l16][quad*8 + 32];
            O[d] = __builtin_amdgcn_mfma_f32_16x16x32_bf16(vf0, pf0, O[d], 0,0,0);
            O[d] = __builtin_amdgcn_mfma_f32_16x16x32_bf16(vf1, pf1, O[d], 0,0,0);
        }
    }

    u16* Ob = Opart + (((size_t)ks*16 + bh)*Sq + q0 + w*16 + l16)*HDh;
    #pragma unroll
    for (int dt=0; dt<4; ++dt){
        u16 pk4[4] = { f2bf(O[dt][0]), f2bf(O[dt][1]),
                       f2bf(O[dt][2]), f2bf(O[dt][3]) };
        *(u64*)(Ob + dt*16 + quad*4) = *(u64*)pk4;
    }
    lsum += __shfl_xor(lsum,16);
    lsum += __shfl_xor(lsum,32);
    if (lane < 16)
        lpart[((size_t)ks*16 + bh)*Sq + q0 + w*16 + l16] = lsum;
}

// ---------------------------------------------------------------------------
// K3: combine 4 bf16 split-K partials -> bf16 A-tile; out-proj + residual +
// LN2 + (x2+h2). 32 rows/block, 512 threads (8 waves), 256 blocks.
// ---------------------------------------------------------------------------
__global__ __launch_bounds__(512) void k3_gemm_ln(
    const u16* __restrict__ Opart, const float* __restrict__ lpart,
    const u16* __restrict__ wTo,
    const float* __restrict__ bo, const float* __restrict__ x1,
    const float* __restrict__ g2, const float* __restrict__ be2,
    float* __restrict__ out)
{
    const int tid  = threadIdx.x;
    const int w    = tid >> 6;            // 0..7
    const int lane = tid & 63;
    const int l16  = lane & 15;
    const int quad = lane >> 4;
    const int r0   = blockIdx.x * 32;
    const int b    = r0 >> 11;
    const int s0   = r0 & (Sq-1);
    const int cA   = w*32 + quad*4;       // +nt*16

    __shared__ u16 Ats[32][264];
    __shared__ float red[2][32][8];
    __shared__ float linv[4][32];

    const size_t LS = (size_t)16*Sq;
    if (tid < 128){
        int h = tid >> 5, r = tid & 31;
        size_t li = ((size_t)(b*Hh + h))*Sq + s0 + r;
        linv[h][r] = 1.f / (lpart[li] + lpart[LS + li]
                          + lpart[2*LS + li] + lpart[3*LS + li]);
    }
    __syncthreads();

    const size_t SPLIT = (size_t)16*Sq*HDh;
    #pragma unroll
    for (int i=0;i<4;++i){
        int idx = i*512 + tid;                 // 2048 items: h x row x c
        int h = idx >> 9, rem = idx & 511, row = rem >> 4, c = rem & 15;
        size_t base = (((size_t)(b*Hh + h))*Sq + s0 + row)*HDh + c*4;
        u64 p0 = *(const u64*)(Opart + base);
        u64 p1 = *(const u64*)(Opart + SPLIT + base);
        u64 p2 = *(const u64*)(Opart + 2*SPLIT + base);
        u64 p3 = *(const u64*)(Opart + 3*SPLIT + base);
        float li = linv[h][row];
        u16 pk[4];
        #pragma unroll
        for (int j=0;j<4;++j){
            float v = bf2f((u32)((p0 >> (16*j)) & 0xffffu))
                    + bf2f((u32)((p1 >> (16*j)) & 0xffffu))
                    + bf2f((u32)((p2 >> (16*j)) & 0xffffu))
                    + bf2f((u32)((p3 >> (16*j)) & 0xffffu));
            pk[j] = f2bf(v*li);
        }
        *(u64*)&Ats[row][h*64 + c*4] = *(u64*)pk;
    }
    __syncthreads();

    frag_cd acc[2][2];
    #pragma unroll
    for (int nt=0;nt<2;++nt){
        float4 b4 = *(const float4*)&bo[cA + nt*16];
        acc[0][nt] = (frag_cd){b4.x, b4.y, b4.z, b4.w};
        acc[1][nt] = acc[0][nt];
    }
    #pragma unroll
    for (int kc=0;kc<8;++kc){
        frag_ab aa0 = *(frag_ab*)&Ats[l16][kc*32 + quad*8];
        frag_ab aa1 = *(frag_ab*)&Ats[16+l16][kc*32 + quad*8];
        #pragma unroll
        for (int nt=0;nt<2;++nt){
            frag_ab wf = *(const frag_ab*)&wTo[(size_t)(w*32+nt*16+l16)*Dd + kc*32 + quad*8];
            acc[0][nt] = __builtin_amdgcn_mfma_f32_16x16x32_bf16(wf, aa0, acc[0][nt], 0,0,0);
            acc[1][nt] = __builtin_amdgcn_mfma_f32_16x16x32_bf16(wf, aa1, acc[1][nt], 0,0,0);
        }
    }

    // x2 = proj + x1 ; LN partials per row-group
    #pragma unroll
    for (int rg=0;rg<2;++rg){
        float s=0.f, q=0.f;
        #pragma unroll
        for (int nt=0;nt<2;++nt){
            float4 r4 = *(const float4*)&x1[(size_t)(r0+rg*16+l16)*Dd + cA + nt*16];
            acc[rg][nt][0] += r4.x; acc[rg][nt][1] += r4.y;
            acc[rg][nt][2] += r4.z; acc[rg][nt][3] += r4.w;
            s += acc[rg][nt][0]+acc[rg][nt][1]+acc[rg][nt][2]+acc[rg][nt][3];
            q += acc[rg][nt][0]*acc[rg][nt][0] + acc[rg][nt][1]*acc[rg][nt][1]
               + acc[rg][nt][2]*acc[rg][nt][2] + acc[rg][nt][3]*acc[rg][nt][3];
        }
        s += __shfl_xor(s,16); q += __shfl_xor(q,16);
        s += __shfl_xor(s,32); q += __shfl_xor(q,32);
        if (lane < 16){ red[0][rg*16+l16][w]=s; red[1][rg*16+l16][w]=q; }
    }
    __syncthreads();

    #pragma unroll
    for (int rg=0;rg<2;++rg){
        int row = rg*16 + l16;
        float s8=0.f, q8=0.f;
        #pragma unroll
        for (int j=0;j<8;++j){ s8 += red[0][row][j]; q8 += red[1][row][j]; }
        float mu = s8*(1.f/Dd), ms = q8*(1.f/Dd);
        float rstd = rsqrtf(ms - mu*mu + EPSf);
        #pragma unroll
        for (int nt=0;nt<2;++nt){
            float4 g4 = *(const float4*)&g2[cA + nt*16];
            float4 e4 = *(const float4*)&be2[cA + nt*16];
            float4 o4;
            o4.x = acc[rg][nt][0] + (acc[rg][nt][0]-mu)*rstd*g4.x + e4.x;
            o4.y = acc[rg][nt][1] + (acc[rg][nt][1]-mu)*rstd*g4.y + e4.y;
            o4.z = acc[rg][nt][2] + (acc[rg][nt][2]-mu)*rstd*g4.z + e4.z;
            o4.w = acc[rg][nt][3] + (acc[rg][nt][3]-mu)*rstd*g4.w + e4.w;
            *(float4*)&out[(size_t)(r0+row)*Dd + cA + nt*16] = o4;
        }
    }
}

// ---------------------------------------------------------------------------
extern "C" void kernel_launch(void* const* d_in, const int* in_sizes, int n_in,
                              void* d_out, int out_size, void* d_ws, size_t ws_size,
                              hipStream_t stream)
{
    const float* x    = (const float*)d_in[0];
    const int*   mask = (const int*)  d_in[1];
    const float* w_in = (const float*)d_in[2];
    const float* b_in = (const float*)d_in[3];
    const float* g1   = (const float*)d_in[4];
    const float* be1  = (const float*)d_in[5];
    const float* wq   = (const float*)d_in[6];
    const float* bq   = (const float*)d_in[7];
    const float* wk   = (const float*)d_in[8];
    const float* bk   = (const float*)d_in[9];
    const float* wv   = (const float*)d_in[10];
    const float* bv   = (const float*)d_in[11];
    const float* wo   = (const float*)d_in[12];
    const float* bo   = (const float*)d_in[13];
    const float* g2   = (const float*)d_in[14];
    const float* be2  = (const float*)d_in[15];
    // inputs 16..21 (gating / experts) provably contribute 0.0 to the output.

    float* out = (float*)d_out;
    char*  wsb = (char*)d_ws;

    float* x1    = (float*)(wsb);                   // 8 MB fp32
    float* tab   = (float*)(wsb + ( 8u<<20));       // 512 KB RoPE table
    u16*   qro   = (u16*)(wsb + (12u<<20));
    u16*   kro   = (u16*)(wsb + (16u<<20));
    u16*   vto   = (u16*)(wsb + (20u<<20));         // [B,H,64,S]
    u16*   Opart = (u16*)(wsb + (24u<<20));         // [4][16][S][64] bf16 = 16 MB
    float* lpart = (float*)(wsb + (40u<<20));       // [4][16][S] fp32 = 512 KB
    u16*   wT    = (u16*)(wsb + (40u<<20) + (768u<<10)); // 5 x 256x256 bf16

    k0_prep<<<336, 256, 0, stream>>>(w_in, wq, wk, wv, wo, wT, tab);
    k1_fused<<<NROWS/32, 512, 0, stream>>>(
        x, tab, wT, wT + Dd*Dd,
        b_in, g1, be1, bq, bk, bv, x1, qro, kro, vto);
    k2_attn<<<dim3(Sq/128, Bb*Hh, 4), 512, 0, stream>>>(qro, kro, vto, mask, Opart, lpart);
    k3_gemm_ln<<<NROWS/32, 512, 0, stream>>>(Opart, lpart, wT + 4*Dd*Dd,
                                             bo, x1, g2, be2, out);
}

// Round 12
// 169.123 us; speedup vs baseline: 1.3403x; 1.0096x over previous
//
#include <hip/hip_runtime.h>
#include <cstddef>

#define Bb    4
#define Sq    2048
#define Dd    256
#define Hh    4
#define HDh   64
#define NROWS (Bb*Sq)     // 8192
#define EPSf  1e-5f

typedef unsigned short u16;
typedef unsigned int   u32;
typedef unsigned long long u64;
typedef __attribute__((ext_vector_type(8))) short  frag_ab;  // 8 bf16 (4 VGPRs)
typedef __attribute__((ext_vector_type(4))) float  frag_cd;  // 4 fp32

__device__ __forceinline__ u16 f2bf(float f){
    union { float f; u32 u; } v; v.f = f;
    u32 r = v.u + 0x7fffu + ((v.u >> 16) & 1u);   // RNE
    return (u16)(r >> 16);
}
__device__ __forceinline__ u16 f2bf_trunc(float f){
    union { float f; u32 u; } v; v.f = f;
    return (u16)(v.u >> 16);                      // 1-op truncation
}
__device__ __forceinline__ float bf2f(u32 u){
    union { u32 u; float f; } v; v.u = u << 16; return v.f;
}

// ---------------------------------------------------------------------------
// K0: prep. blocks 0..79: transpose+convert 5 weights -> wT[n][k] bf16
// (order: w_in, wq, wk, wv, wo — wq|wk|wv contiguous 768x256).
//     blocks 80..335: RoPE table tab[s][0..31]=cos, [32..63]=sin.
// ---------------------------------------------------------------------------
__global__ __launch_bounds__(256) void k0_prep(
    const float* __restrict__ w_in, const float* __restrict__ wq,
    const float* __restrict__ wk,   const float* __restrict__ wv,
    const float* __restrict__ wo,
    u16* __restrict__ wT, float* __restrict__ tab)
{
    const int bid = blockIdx.x, tid = threadIdx.x;
    if (bid < 80){
        __shared__ float T[64][65];
        const int wsel = bid >> 4, tile = bid & 15;
        const int k0 = (tile >> 2) * 64, n0 = (tile & 3) * 64;
        const float* src = wsel==0 ? w_in : wsel==1 ? wq : wsel==2 ? wk
                         : wsel==3 ? wv : wo;
        #pragma unroll
        for (int i=0;i<16;++i){
            int idx = i*256 + tid, k = idx>>6, n = idx&63;
            T[k][n] = src[(size_t)(k0+k)*Dd + n0 + n];
        }
        __syncthreads();
        u16* dst = wT + (size_t)wsel*Dd*Dd;
        #pragma unroll
        for (int i=0;i<16;++i){
            int idx = i*256 + tid, n = idx>>6, k = idx&63;
            dst[(size_t)(n0+n)*Dd + k0 + k] = f2bf(T[k][n]);
        }
    } else {
        int s = (bid-80)*8 + (tid>>5);
        int p = tid & 31;
        float invf = exp2f(-(float)p * (13.287712379549449f/32.f)); // log2(1e4)/32
        float sn, cs; sincosf((float)s * invf, &sn, &cs);
        tab[(size_t)s*64 + p]      = cs;
        tab[(size_t)s*64 + 32 + p] = sn;
    }
}

// ---------------------------------------------------------------------------
// K1 fused: 32 rows/block, 512 threads (8 waves), 256 blocks (1/CU).
// Phase A: in-proj (wave owns 32 cols) -> x1 bf16. Phase B: merged QKV GEMM
// over contiguous wqkv [768x256] (wave owns 96 cols). RoPE q/k + V^T out.
// ---------------------------------------------------------------------------
__global__ __launch_bounds__(512) void k1_fused(
    const float* __restrict__ x,  const float* __restrict__ tab,
    const u16* __restrict__ wTin, const u16* __restrict__ wTqkv,
    const float* __restrict__ b_in, const float* __restrict__ g1,
    const float* __restrict__ be1,  const float* __restrict__ bq,
    const float* __restrict__ bk,   const float* __restrict__ bv,
    u16* __restrict__ x1, u16* __restrict__ qro,
    u16* __restrict__ kro,  u16* __restrict__ vto)
{
    const int tid  = threadIdx.x;
    const int w    = tid >> 6;            // 0..7
    const int lane = tid & 63;
    const int l16  = lane & 15;
    const int quad = lane >> 4;
    const int r0   = blockIdx.x * 32;
    const int b    = r0 >> 11;
    const int s0   = r0 & (Sq-1);

    __shared__ u16 Xs[32][264];
    __shared__ u16 Hs[32][264];
    __shared__ u16 Os[32][776];           // 768 cols + pad
    __shared__ float red[2][32][8];

    // stage x tile: 32 rows x 256 cols, fp32->bf16 (2048 float4 / 512 thr)
    #pragma unroll
    for (int i=0;i<4;++i){
        int f = i*512 + tid;
        int row = f>>6, cc = f&63;
        float4 v4 = *(const float4*)(x + (size_t)(r0+row)*Dd + cc*4);
        u16 pk4[4] = { f2bf(v4.x), f2bf(v4.y), f2bf(v4.z), f2bf(v4.w) };
        *(u64*)&Xs[row][cc*4] = *(u64*)pk4;
    }
    __syncthreads();

    // ---- Phase A: in-proj, wave owns cols [w*32, w*32+32) ----
    const int cA = w*32 + quad*4;         // +nt*16
    frag_cd acc[2][2];
    #pragma unroll
    for (int nt=0;nt<2;++nt){
        float4 b4 = *(const float4*)&b_in[cA + nt*16];
        acc[0][nt] = (frag_cd){b4.x, b4.y, b4.z, b4.w};
        acc[1][nt] = acc[0][nt];
    }
    #pragma unroll
    for (int kc=0;kc<8;++kc){
        frag_ab xa0 = *(frag_ab*)&Xs[l16][kc*32 + quad*8];
        frag_ab xa1 = *(frag_ab*)&Xs[16+l16][kc*32 + quad*8];
        #pragma unroll
        for (int nt=0;nt<2;++nt){
            frag_ab wf = *(const frag_ab*)&wTin[(size_t)(w*32+nt*16+l16)*Dd + kc*32 + quad*8];
            acc[0][nt] = __builtin_amdgcn_mfma_f32_16x16x32_bf16(wf, xa0, acc[0][nt], 0,0,0);
            acc[1][nt] = __builtin_amdgcn_mfma_f32_16x16x32_bf16(wf, xa1, acc[1][nt], 0,0,0);
        }
    }

    // x1 store (bf16 u64) + LN partials
    #pragma unroll
    for (int rg=0;rg<2;++rg){
        float s=0.f, q=0.f;
        #pragma unroll
        for (int nt=0;nt<2;++nt){
            float v0=acc[rg][nt][0], v1=acc[rg][nt][1],
                  v2=acc[rg][nt][2], v3=acc[rg][nt][3];
            u16 pk4[4] = { f2bf(v0), f2bf(v1), f2bf(v2), f2bf(v3) };
            *(u64*)&x1[(size_t)(r0+rg*16+l16)*Dd + cA + nt*16] = *(u64*)pk4;
            s += v0+v1+v2+v3;
            q += v0*v0 + v1*v1 + v2*v2 + v3*v3;
        }
        s += __shfl_xor(s,16); q += __shfl_xor(q,16);
        s += __shfl_xor(s,32); q += __shfl_xor(q,32);
        if (lane < 16){ red[0][rg*16+l16][w]=s; red[1][rg*16+l16][w]=q; }
    }
    __syncthreads();

    #pragma unroll
    for (int rg=0;rg<2;++rg){
        int row = rg*16 + l16;
        float s8=0.f, q8=0.f;
        #pragma unroll
        for (int j=0;j<8;++j){ s8 += red[0][row][j]; q8 += red[1][row][j]; }
        float mu = s8*(1.f/Dd), ms = q8*(1.f/Dd);
        float rstd = rsqrtf(ms - mu*mu + EPSf);
        #pragma unroll
        for (int nt=0;nt<2;++nt){
            float4 g4 = *(const float4*)&g1[cA + nt*16];
            float4 e4 = *(const float4*)&be1[cA + nt*16];
            u16 pk4[4] = { f2bf((acc[rg][nt][0]-mu)*rstd*g4.x + e4.x),
                           f2bf((acc[rg][nt][1]-mu)*rstd*g4.y + e4.y),
                           f2bf((acc[rg][nt][2]-mu)*rstd*g4.z + e4.z),
                           f2bf((acc[rg][nt][3]-mu)*rstd*g4.w + e4.w) };
            *(u64*)&Hs[rg*16+l16][cA + nt*16] = *(u64*)pk4;
        }
    }
    __syncthreads();

    // ---- Phase B: merged QKV, wave owns cols [w*96, w*96+96) of 768 ----
    frag_cd a2[2][6];
    #pragma unroll
    for (int nt=0;nt<6;++nt){
        int c0 = w*96 + nt*16;
        const float* bp = (c0 < 256) ? bq : (c0 < 512 ? bk : bv);
        int cc = (c0 & 255) + quad*4;
        float4 b4 = *(const float4*)&bp[cc];
        a2[0][nt] = (frag_cd){b4.x, b4.y, b4.z, b4.w};
        a2[1][nt] = a2[0][nt];
    }
    #pragma unroll
    for (int kc=0;kc<8;++kc){
        frag_ab ha0 = *(frag_ab*)&Hs[l16][kc*32 + quad*8];
        frag_ab ha1 = *(frag_ab*)&Hs[16+l16][kc*32 + quad*8];
        #pragma unroll
        for (int nt=0;nt<6;++nt){
            frag_ab wf = *(const frag_ab*)&wTqkv[(size_t)(w*96+nt*16+l16)*Dd + kc*32 + quad*8];
            a2[0][nt] = __builtin_amdgcn_mfma_f32_16x16x32_bf16(wf, ha0, a2[0][nt], 0,0,0);
            a2[1][nt] = __builtin_amdgcn_mfma_f32_16x16x32_bf16(wf, ha1, a2[1][nt], 0,0,0);
        }
    }
    #pragma unroll
    for (int rg=0;rg<2;++rg)
        #pragma unroll
        for (int nt=0;nt<6;++nt){
            u16 pk4[4] = { f2bf(a2[rg][nt][0]), f2bf(a2[rg][nt][1]),
                           f2bf(a2[rg][nt][2]), f2bf(a2[rg][nt][3]) };
            *(u64*)&Os[rg*16+l16][w*96 + nt*16 + quad*4] = *(u64*)pk4;
        }
    __syncthreads();

    // ---- Epilogues (Os: q=0..255, k=256..511, v=512..767) ----
    {   // RoPE q and k
        const int row  = tid >> 4;
        const int head = (tid >> 2) & 3;
        const int pq   = tid & 3;
        const int sidx = s0 + row;
        const float* tb = tab + (size_t)sidx*64;
        float4 c0 = *(const float4*)(tb + pq*8);
        float4 c1 = *(const float4*)(tb + pq*8 + 4);
        float4 sn0 = *(const float4*)(tb + 32 + pq*8);
        float4 sn1 = *(const float4*)(tb + 32 + pq*8 + 4);
        const float cAr[8] = {c0.x,c0.y,c0.z,c0.w,c1.x,c1.y,c1.z,c1.w};
        const float sAr[8] = {sn0.x,sn0.y,sn0.z,sn0.w,sn1.x,sn1.y,sn1.z,sn1.w};
        #pragma unroll
        for (int tt=0; tt<2; ++tt){
            const int cbase = tt*256 + head*64;
            u16* dst = (tt==0 ? qro : kro) + ((size_t)(b*Hh+head)*Sq + sidx)*HDh;
            u16 lo[8], hi[8];
            #pragma unroll
            for (int j=0;j<8;++j){
                int p = pq*8 + j;
                u32 pr = *(const u32*)&Os[row][cbase + 2*p];
                float t0 = bf2f(pr & 0xffffu), t1 = bf2f(pr >> 16);
                lo[j] = f2bf(t0*cAr[j] - t1*sAr[j]);
                hi[j] = f2bf(t1*cAr[j] + t0*sAr[j]);
            }
            *(float4*)(dst + pq*8)      = *(float4*)lo;
            *(float4*)(dst + 32 + pq*8) = *(float4*)hi;
        }
    }
    {   // V^T
        const int head = tid >> 7, d = (tid >> 1) & 63, rg = tid & 1;
        u16 pk[16];
        #pragma unroll
        for (int j=0;j<16;++j) pk[j] = Os[rg*16+j][512 + head*64 + d];
        u16* dst = vto + ((size_t)(b*Hh+head)*HDh + d)*Sq + s0 + rg*16;
        *(float4*)dst     = *(float4*)pk;
        *(float4*)(dst+8) = *(float4*)&pk[8];
    }
}

// ---------------------------------------------------------------------------
// K2: bf16 MFMA flash attention. 256-query blocks (8 waves x 2 row-groups),
// split-K x4 -> grid (8,16,4)=512 blocks = 2/CU, 16 waves/CU. Each staged
// K/V tile feeds 2x the MFMAs (K/V L2 traffic halved vs 128-q version).
// ---------------------------------------------------------------------------
__global__ __launch_bounds__(512) void k2_attn(
    const u16* __restrict__ qr, const u16* __restrict__ kr,
    const u16* __restrict__ vt, const int* __restrict__ mask,
    u16* __restrict__ Opart, float* __restrict__ lpart)
{
    const int tid = threadIdx.x;
    const int w   = tid >> 6;          // 0..7
    const int lane= tid & 63;
    const int l16 = lane & 15;
    const int quad= lane >> 4;
    const int qt  = blockIdx.x;        // 0..7
    const int bh  = blockIdx.y;        // 0..15
    const int ks  = blockIdx.z;        // 0..3 (512 keys each)
    const int b   = bh >> 2;
    const int q0  = qt * 256;

    __shared__ u16 Ks [64][72];
    __shared__ u16 Vts[64][72];
    __shared__ u16 Ps [8][2][16][72];

    // Q fragments: rg0 = q0 + w*16, rg1 = q0 + 128 + w*16
    frag_ab qf[2][2];
    float mf2[2];
    #pragma unroll
    for (int rg=0;rg<2;++rg){
        const u16* qg = qr + ((size_t)bh*Sq + q0 + rg*128 + w*16 + l16)*HDh;
        qf[rg][0] = *(const frag_ab*)(qg + quad*8);
        qf[rg][1] = *(const frag_ab*)(qg + quad*8 + 32);
        mf2[rg] = (mask[(size_t)b*Sq + q0 + rg*128 + w*16 + l16] != 0)
                ? 0.125f*1.44269504f : 0.f;
    }

    float lsum[2] = {0.f, 0.f};
    frag_cd O[2][4];
    #pragma unroll
    for (int rg=0;rg<2;++rg)
        #pragma unroll
        for (int d=0; d<4; ++d) O[rg][d] = (frag_cd){0.f,0.f,0.f,0.f};

    const u16* kg0 = kr + ((size_t)bh*Sq + ks*512)*HDh;
    const u16* vg0 = vt + (size_t)bh*HDh*Sq + ks*512;

    const int srow = tid >> 3, spart = tid & 7;

    for (int kt=0; kt<8; ++kt){
        __syncthreads();
        const u16* kg = kg0 + (size_t)kt*64*HDh;
        const u16* vg = vg0 + kt*64;
        *(float4*)&Ks [srow][spart*8] = *(const float4*)(kg + srow*HDh + spart*8);
        *(float4*)&Vts[srow][spart*8] = *(const float4*)(vg + (size_t)srow*Sq + spart*8);
        __syncthreads();

        #pragma unroll
        for (int rg=0;rg<2;++rg){
            frag_cd sc[4];
            #pragma unroll
            for (int t=0;t<4;++t){
                frag_ab kf0 = *(frag_ab*)&Ks[t*16 + l16][quad*8];
                frag_ab kf1 = *(frag_ab*)&Ks[t*16 + l16][quad*8 + 32];
                frag_cd z = (frag_cd){0.f,0.f,0.f,0.f};
                z = __builtin_amdgcn_mfma_f32_16x16x32_bf16(kf0, qf[rg][0], z, 0,0,0);
                z = __builtin_amdgcn_mfma_f32_16x16x32_bf16(kf1, qf[rg][1], z, 0,0,0);
                sc[t] = z;
            }

            #pragma unroll
            for (int t=0;t<4;++t){
                float p0 = exp2f(sc[t][0]*mf2[rg]);
                float p1 = exp2f(sc[t][1]*mf2[rg]);
                float p2 = exp2f(sc[t][2]*mf2[rg]);
                float p3 = exp2f(sc[t][3]*mf2[rg]);
                lsum[rg] += p0+p1+p2+p3;
                u16 pk4[4] = { f2bf_trunc(p0), f2bf_trunc(p1),
                               f2bf_trunc(p2), f2bf_trunc(p3) };
                *(u64*)&Ps[w][rg][l16][t*16 + quad*4] = *(u64*)pk4;
            }

            frag_ab pf0 = *(frag_ab*)&Ps[w][rg][l16][quad*8];
            frag_ab pf1 = *(frag_ab*)&Ps[w][rg][l16][quad*8 + 32];

            #pragma unroll
            for (int d=0; d<4; ++d){
                frag_ab vf0 = *(frag_ab*)&Vts[d*16 + l16][quad*8];
                frag_ab vf1 = *(frag_ab*)&Vts[d*16 + l16][quad*8 + 32];
                O[rg][d] = __builtin_amdgcn_mfma_f32_16x16x32_bf16(vf0, pf0, O[rg][d], 0,0,0);
                O[rg][d] = __builtin_amdgcn_mfma_f32_16x16x32_bf16(vf1, pf1, O[rg][d], 0,0,0);
            }
        }
    }

    #pragma unroll
    for (int rg=0;rg<2;++rg){
        u16* Ob = Opart + (((size_t)ks*16 + bh)*Sq + q0 + rg*128 + w*16 + l16)*HDh;
        #pragma unroll
        for (int dt=0; dt<4; ++dt){
            u16 pk4[4] = { f2bf(O[rg][dt][0]), f2bf(O[rg][dt][1]),
                           f2bf(O[rg][dt][2]), f2bf(O[rg][dt][3]) };
            *(u64*)(Ob + dt*16 + quad*4) = *(u64*)pk4;
        }
        float s = lsum[rg];
        s += __shfl_xor(s,16);
        s += __shfl_xor(s,32);
        if (lane < 16)
            lpart[((size_t)ks*16 + bh)*Sq + q0 + rg*128 + w*16 + l16] = s;
    }
}

// ---------------------------------------------------------------------------
// K3: combine 4 bf16 split-K partials -> bf16 A-tile; out-proj + residual
// (bf16 x1) + LN2 + (x2+h2). 32 rows/block, 512 threads, 256 blocks.
// ---------------------------------------------------------------------------
__global__ __launch_bounds__(512) void k3_gemm_ln(
    const u16* __restrict__ Opart, const float* __restrict__ lpart,
    const u16* __restrict__ wTo,
    const float* __restrict__ bo, const u16* __restrict__ x1,
    const float* __restrict__ g2, const float* __restrict__ be2,
    float* __restrict__ out)
{
    const int tid  = threadIdx.x;
    const int w    = tid >> 6;            // 0..7
    const int lane = tid & 63;
    const int l16  = lane & 15;
    const int quad = lane >> 4;
    const int r0   = blockIdx.x * 32;
    const int b    = r0 >> 11;
    const int s0   = r0 & (Sq-1);
    const int cA   = w*32 + quad*4;       // +nt*16

    __shared__ u16 Ats[32][264];
    __shared__ float red[2][32][8];
    __shared__ float linv[4][32];

    const size_t LS = (size_t)16*Sq;
    if (tid < 128){
        int h = tid >> 5, r = tid & 31;
        size_t li = ((size_t)(b*Hh + h))*Sq + s0 + r;
        linv[h][r] = 1.f / (lpart[li] + lpart[LS + li]
                          + lpart[2*LS + li] + lpart[3*LS + li]);
    }
    __syncthreads();

    const size_t SPLIT = (size_t)16*Sq*HDh;
    #pragma unroll
    for (int i=0;i<4;++i){
        int idx = i*512 + tid;                 // 2048 items: h x row x c
        int h = idx >> 9, rem = idx & 511, row = rem >> 4, c = rem & 15;
        size_t base = (((size_t)(b*Hh + h))*Sq + s0 + row)*HDh + c*4;
        u64 p0 = *(const u64*)(Opart + base);
        u64 p1 = *(const u64*)(Opart + SPLIT + base);
        u64 p2 = *(const u64*)(Opart + 2*SPLIT + base);
        u64 p3 = *(const u64*)(Opart + 3*SPLIT + base);
        float li = linv[h][row];
        u16 pk[4];
        #pragma unroll
        for (int j=0;j<4;++j){
            float v = bf2f((u32)((p0 >> (16*j)) & 0xffffu))
                    + bf2f((u32)((p1 >> (16*j)) & 0xffffu))
                    + bf2f((u32)((p2 >> (16*j)) & 0xffffu))
                    + bf2f((u32)((p3 >> (16*j)) & 0xffffu));
            pk[j] = f2bf(v*li);
        }
        *(u64*)&Ats[row][h*64 + c*4] = *(u64*)pk;
    }
    __syncthreads();

    frag_cd acc[2][2];
    #pragma unroll
    for (int nt=0;nt<2;++nt){
        float4 b4 = *(const float4*)&bo[cA + nt*16];
        acc[0][nt] = (frag_cd){b4.x, b4.y, b4.z, b4.w};
        acc[1][nt] = acc[0][nt];
    }
    #pragma unroll
    for (int kc=0;kc<8;++kc){
        frag_ab aa0 = *(frag_ab*)&Ats[l16][kc*32 + quad*8];
        frag_ab aa1 = *(frag_ab*)&Ats[16+l16][kc*32 + quad*8];
        #pragma unroll
        for (int nt=0;nt<2;++nt){
            frag_ab wf = *(const frag_ab*)&wTo[(size_t)(w*32+nt*16+l16)*Dd + kc*32 + quad*8];
            acc[0][nt] = __builtin_amdgcn_mfma_f32_16x16x32_bf16(wf, aa0, acc[0][nt], 0,0,0);
            acc[1][nt] = __builtin_amdgcn_mfma_f32_16x16x32_bf16(wf, aa1, acc[1][nt], 0,0,0);
        }
    }

    // x2 = proj + x1 (bf16 residual) ; LN partials
    #pragma unroll
    for (int rg=0;rg<2;++rg){
        float s=0.f, q=0.f;
        #pragma unroll
        for (int nt=0;nt<2;++nt){
            u64 r8 = *(const u64*)&x1[(size_t)(r0+rg*16+l16)*Dd + cA + nt*16];
            acc[rg][nt][0] += bf2f((u32)( r8        & 0xffffu));
            acc[rg][nt][1] += bf2f((u32)((r8 >> 16) & 0xffffu));
            acc[rg][nt][2] += bf2f((u32)((r8 >> 32) & 0xffffu));
            acc[rg][nt][3] += bf2f((u32)((r8 >> 48) & 0xffffu));
            s += acc[rg][nt][0]+acc[rg][nt][1]+acc[rg][nt][2]+acc[rg][nt][3];
            q += acc[rg][nt][0]*acc[rg][nt][0] + acc[rg][nt][1]*acc[rg][nt][1]
               + acc[rg][nt][2]*acc[rg][nt][2] + acc[rg][nt][3]*acc[rg][nt][3];
        }
        s += __shfl_xor(s,16); q += __shfl_xor(q,16);
        s += __shfl_xor(s,32); q += __shfl_xor(q,32);
        if (lane < 16){ red[0][rg*16+l16][w]=s; red[1][rg*16+l16][w]=q; }
    }
    __syncthreads();

    #pragma unroll
    for (int rg=0;rg<2;++rg){
        int row = rg*16 + l16;
        float s8=0.f, q8=0.f;
        #pragma unroll
        for (int j=0;j<8;++j){ s8 += red[0][row][j]; q8 += red[1][row][j]; }
        float mu = s8*(1.f/Dd), ms = q8*(1.f/Dd);
        float rstd = rsqrtf(ms - mu*mu + EPSf);
        #pragma unroll
        for (int nt=0;nt<2;++nt){
            float4 g4 = *(const float4*)&g2[cA + nt*16];
            float4 e4 = *(const float4*)&be2[cA + nt*16];
            float4 o4;
            o4.x = acc[rg][nt][0] + (acc[rg][nt][0]-mu)*rstd*g4.x + e4.x;
            o4.y = acc[rg][nt][1] + (acc[rg][nt][1]-mu)*rstd*g4.y + e4.y;
            o4.z = acc[rg][nt][2] + (acc[rg][nt][2]-mu)*rstd*g4.z + e4.z;
            o4.w = acc[rg][nt][3] + (acc[rg][nt][3]-mu)*rstd*g4.w + e4.w;
            *(float4*)&out[(size_t)(r0+row)*Dd + cA + nt*16] = o4;
        }
    }
}

// ---------------------------------------------------------------------------
extern "C" void kernel_launch(void* const* d_in, const int* in_sizes, int n_in,
                              void* d_out, int out_size, void* d_ws, size_t ws_size,
                              hipStream_t stream)
{
    const float* x    = (const float*)d_in[0];
    const int*   mask = (const int*)  d_in[1];
    const float* w_in = (const float*)d_in[2];
    const float* b_in = (const float*)d_in[3];
    const float* g1   = (const float*)d_in[4];
    const float* be1  = (const float*)d_in[5];
    const float* wq   = (const float*)d_in[6];
    const float* bq   = (const float*)d_in[7];
    const float* wk   = (const float*)d_in[8];
    const float* bk   = (const float*)d_in[9];
    const float* wv   = (const float*)d_in[10];
    const float* bv   = (const float*)d_in[11];
    const float* wo   = (const float*)d_in[12];
    const float* bo   = (const float*)d_in[13];
    const float* g2   = (const float*)d_in[14];
    const float* be2  = (const float*)d_in[15];
    // inputs 16..21 (gating / experts) provably contribute 0.0 to the output.

    float* out = (float*)d_out;
    char*  wsb = (char*)d_ws;

    u16*   x1    = (u16*)(wsb);                     // 4 MB bf16
    float* tab   = (float*)(wsb + ( 8u<<20));       // 512 KB RoPE table
    u16*   qro   = (u16*)(wsb + (12u<<20));
    u16*   kro   = (u16*)(wsb + (16u<<20));
    u16*   vto   = (u16*)(wsb + (20u<<20));         // [B,H,64,S]
    u16*   Opart = (u16*)(wsb + (24u<<20));         // [4][16][S][64] bf16 = 16 MB
    float* lpart = (float*)(wsb + (40u<<20));       // [4][16][S] fp32 = 512 KB
    u16*   wT    = (u16*)(wsb + (40u<<20) + (768u<<10)); // 5 x 256x256 bf16

    k0_prep<<<336, 256, 0, stream>>>(w_in, wq, wk, wv, wo, wT, tab);
    k1_fused<<<NROWS/32, 512, 0, stream>>>(
        x, tab, wT, wT + Dd*Dd,
        b_in, g1, be1, bq, bk, bv, x1, qro, kro, vto);
    k2_attn<<<dim3(Sq/256, Bb*Hh, 4), 512, 0, stream>>>(qro, kro, vto, mask, Opart, lpart);
    k3_gemm_ln<<<NROWS/32, 512, 0, stream>>>(Opart, lpart, wT + 4*Dd*Dd,
                                             bo, x1, g2, be2, out);
}